// Round 17
// baseline (180.822 us; speedup 1.0000x reference)
//
#include <hip/hip_runtime.h>
#include <math.h>

#define NN 100000
#define NE 1600000
#define HID 64
#define OUTC 32
#define NBUCK 196      // ceil(100000/512) buckets of 512 dst nodes
#define NPB 512        // partition blocks
#define EPB 3125       // edges per partition block (NPB*EPB == NE)
#define MAXB 10240     // fixed staging stride per bucket (mean 8192, sigma~90)
#define LOG2E 1.44269504088896340736f

typedef float f32x2 __attribute__((ext_vector_type(2)));

__device__ __forceinline__ f32x2 pk_mul(f32x2 a, f32x2 b) {
    f32x2 r;
    asm("v_pk_mul_f32 %0, %1, %2" : "=v"(r) : "v"(a), "v"(b));
    return r;
}
__device__ __forceinline__ f32x2 pk_fma(f32x2 a, f32x2 b, f32x2 c) {
    f32x2 r;
    asm("v_pk_fma_f32 %0, %1, %2, %3" : "=v"(r) : "v"(a), "v"(b), "v"(c));
    return r;
}
__device__ __forceinline__ f32x2 pk_add(f32x2 a, f32x2 b) {
    f32x2 r;
    asm("v_pk_add_f32 %0, %1, %2" : "=v"(r) : "v"(a), "v"(b));
    return r;
}
// broadcast lo/hi word of src0 across both halves (no movs)
__device__ __forceinline__ f32x2 pk_fma_blo(f32x2 x, f32x2 b, f32x2 c) {
    f32x2 r;
    asm("v_pk_fma_f32 %0, %1, %2, %3 op_sel:[0,0,0] op_sel_hi:[0,1,1]" : "=v"(r) : "v"(x), "v"(b), "v"(c));
    return r;
}
__device__ __forceinline__ f32x2 pk_fma_bhi(f32x2 x, f32x2 b, f32x2 c) {
    f32x2 r;
    asm("v_pk_fma_f32 %0, %1, %2, %3 op_sel:[1,0,0] op_sel_hi:[1,1,1]" : "=v"(r) : "v"(x), "v"(b), "v"(c));
    return r;
}
__device__ __forceinline__ f32x2 pk_mul_bhi(f32x2 x, f32x2 b) {
    f32x2 r;
    asm("v_pk_mul_f32 %0, %1, %2 op_sel:[1,0] op_sel_hi:[1,1]" : "=v"(r) : "v"(x), "v"(b));
    return r;
}
__device__ __forceinline__ f32x2 pk_abs(f32x2 a) {
    f32x2 r;
    r.x = __builtin_fabsf(a.x);
    r.y = __builtin_fabsf(a.y);
    return r;
}
__device__ __forceinline__ unsigned short f2bf(float f) {
    unsigned int u = __float_as_uint(f);
    u += 0x7FFFu + ((u >> 16) & 1u);
    return (unsigned short)(u >> 16);
}
// quad-level butterfly adds via DPP (VALU only, no DS)
__device__ __forceinline__ float quad_add_xor1(float v) {
    int t = __builtin_amdgcn_mov_dpp(__float_as_int(v), 0xB1, 0xF, 0xF, true);  // [1,0,3,2]
    return v + __int_as_float(t);
}
__device__ __forceinline__ float quad_add_xor2(float v) {
    int t = __builtin_amdgcn_mov_dpp(__float_as_int(v), 0x4E, 0xF, 0xF, true);  // [2,3,0,1]
    return v + __int_as_float(t);
}
__device__ __forceinline__ float ex2(float v) {  // 2^v
    float r;
    asm("v_exp_f32 %0, %1" : "=v"(r) : "v"(v));
    return r;
}

// ---------- CSR build: bucket sort with fixed-stride staging ----------

// one pass: LDS hist -> chunk reserve (global atomic per bucket) -> scatter
__global__ __launch_bounds__(256) void bucketB_kernel(const int* __restrict__ ei,
                                                      int* __restrict__ gcount,
                                                      unsigned int* __restrict__ staging) {
    __shared__ int cnt[NBUCK];
    __shared__ int cur[NBUCK];
    int tid = threadIdx.x;
    for (int i = tid; i < NBUCK; i += 256) cnt[i] = 0;
    __syncthreads();
    int base = blockIdx.x * EPB;
    const int* dstp = ei + NE;
    for (int i = tid; i < EPB; i += 256) atomicAdd(&cnt[dstp[base + i] >> 9], 1);
    __syncthreads();
    for (int i = tid; i < NBUCK; i += 256)
        cur[i] = i * MAXB + atomicAdd(&gcount[i], cnt[i]);
    __syncthreads();
    for (int i = tid; i < EPB; i += 256) {
        int d = dstp[base + i];
        int s = ei[base + i];
        int pos = atomicAdd(&cur[d >> 9], 1);
        staging[pos] = ((unsigned int)(d & 511) << 17) | (unsigned int)s;
    }
}

// exclusive prefix of the 196 bucket totals (1 block)
__global__ __launch_bounds__(256) void scanG_kernel(const int* __restrict__ gcount,
                                                    int* __restrict__ gbase) {
    __shared__ int sbuf[256];
    int tid = threadIdx.x;
    int v = (tid < NBUCK) ? gcount[tid] : 0;
    int run = v;
    sbuf[tid] = run;
    __syncthreads();
    for (int off = 1; off < 256; off <<= 1) {
        int u = (tid >= off) ? sbuf[tid - off] : 0;
        __syncthreads();
        run += u;
        sbuf[tid] = run;
        __syncthreads();
    }
    if (tid < NBUCK) gbase[tid] = run - v;
    if (tid == 0) gbase[NBUCK] = NE;
}

// per bucket: LDS node histogram + scan -> rowptr, then LDS-cursor scatter -> csr_src
__global__ __launch_bounds__(256) void bucketC_kernel(const unsigned int* __restrict__ staging,
                                                      const int* __restrict__ gcount,
                                                      const int* __restrict__ gbase,
                                                      int* __restrict__ rowptr,
                                                      int* __restrict__ csr_src) {
    int b = blockIdx.x;
    int node0 = b << 9;
    int nnode = min(512, NN - node0);
    int ecnt = gcount[b];
    int e0 = gbase[b];
    const unsigned int* st = staging + (size_t)b * MAXB;
    __shared__ int deg[512];
    __shared__ int sbuf[256];
    int tid = threadIdx.x;
    deg[tid] = 0;
    deg[tid + 256] = 0;
    __syncthreads();
    for (int e = tid; e < ecnt; e += 256) atomicAdd(&deg[st[e] >> 17], 1);
    __syncthreads();
    int d0 = deg[2 * tid], d1 = deg[2 * tid + 1];
    int tsum = d0 + d1;
    int run = tsum;
    sbuf[tid] = tsum;
    __syncthreads();
    for (int off = 1; off < 256; off <<= 1) {
        int u = (tid >= off) ? sbuf[tid - off] : 0;
        __syncthreads();
        run += u;
        sbuf[tid] = run;
        __syncthreads();
    }
    int eb = run - tsum;
    deg[2 * tid] = eb;
    deg[2 * tid + 1] = eb + d0;
    if (2 * tid < nnode) rowptr[node0 + 2 * tid] = e0 + eb;
    if (2 * tid + 1 < nnode) rowptr[node0 + 2 * tid + 1] = e0 + eb + d0;
    if (b == NBUCK - 1 && tid == 0) rowptr[NN] = NE;
    __syncthreads();
    for (int e = tid; e < ecnt; e += 256) {
        unsigned int p = st[e];
        int dl = p >> 17;
        int src = (int)(p & 0x1FFFFu);
        int pos = e0 + atomicAdd(&deg[dl], 1);
        csr_src[pos] = src;
    }
}

// ---------- layer 1: fully fused gather (no lin2 fusion); 2 nodes per wave ----------

#define PROC1(X, IDX, MASKED)                                                 \
    {                                                                         \
        f32x2 Xxy = {X.x, X.y}, Xzw = {X.z, X.w};                             \
        f32x2 s01 = pk_fma_blo(Xxy, wl0_01, pk_fma_bhi(Xxy, wl1_01,           \
                    pk_fma_blo(Xzw, wl2_01, pk_fma_bhi(Xzw, wl3_01, xr01)))); \
        f32x2 s23 = pk_fma_blo(Xxy, wl0_23, pk_fma_bhi(Xxy, wl1_23,           \
                    pk_fma_blo(Xzw, wl2_23, pk_fma_bhi(Xzw, wl3_23, xr23)))); \
        f32x2 t01 = pk_abs(s01), t23 = pk_abs(s23);                           \
        f32x2 dd = pk_fma(s01, a06_01, pk_fma(t01, a04_01,                    \
                   pk_fma(s23, a06_23, pk_mul(t23, a04_23))));                \
        float vv = dd.x + dd.y;                                               \
        vv = quad_add_xor1(vv);                                               \
        vv = quad_add_xor2(vv);  /* 4-lane quad -> 16-ch head logit (log2) */ \
        float ev = ex2(vv);                                                   \
        if (MASKED && (IDX) >= cnt) ev = 0.f;                                 \
        ssum += ev;                                                           \
        f32x2 ev2 = {ev, ev};                                                 \
        accA = pk_fma(ev2, Xxy, accA);                                        \
        accB = pk_fma(ev2, Xzw, accB);                                        \
    }

// half-wave (32 lanes) per dst node; 2 edge slots (grp) x 16 lanes (4 ch each).
__global__ __launch_bounds__(256) void gather1_kernel(const int* __restrict__ rowptr,
                                                      const int* __restrict__ csr_src,
                                                      const float* __restrict__ x,
                                                      const float* __restrict__ Wl,
                                                      const float* __restrict__ Wr,
                                                      const float* __restrict__ att,
                                                      const float* __restrict__ b1,
                                                      const float* __restrict__ g1,
                                                      const float* __restrict__ be1,
                                                      float* __restrict__ h) {
    __shared__ float sWl[4 * HID], sWr[4 * HID];
    __shared__ float satt[HID], sb[HID], sg[HID], sbe[HID];
    int tid = threadIdx.x;
    if (tid < 256) {
        sWl[tid] = Wl[tid];
        sWr[tid] = Wr[tid];
    }
    if (tid < HID) {
        satt[tid] = att[tid];
        sb[tid] = b1[tid];
        sg[tid] = g1[tid];
        sbe[tid] = be1[tid];
    }
    __syncthreads();
    int node = blockIdx.x * 8 + (tid >> 5);   // 8 half-waves per block; grid*8 == NN exactly
    int lane = tid & 63;
    int hbase = lane & 32;   // 0 or 32: this half's lane base
    int ln = lane & 31;      // lane within half
    int grp = ln >> 4;       // edge slot 0..1
    int ch = (ln & 15) * 4;
    int p0 = rowptr[node], p1 = rowptr[node + 1];

    f32x2 wl0_01 = {sWl[ch + 0], sWl[ch + 1]},            wl0_23 = {sWl[ch + 2], sWl[ch + 3]};
    f32x2 wl1_01 = {sWl[64 + ch + 0], sWl[64 + ch + 1]},  wl1_23 = {sWl[64 + ch + 2], sWl[64 + ch + 3]};
    f32x2 wl2_01 = {sWl[128 + ch + 0], sWl[128 + ch + 1]}, wl2_23 = {sWl[128 + ch + 2], sWl[128 + ch + 3]};
    f32x2 wl3_01 = {sWl[192 + ch + 0], sWl[192 + ch + 1]}, wl3_23 = {sWl[192 + ch + 2], sWl[192 + ch + 3]};

    float4 xd = *(const float4*)(x + node * 4);
    f32x2 Dxy = {xd.x, xd.y}, Dzw = {xd.z, xd.w};
    f32x2 wr0_01 = {sWr[ch + 0], sWr[ch + 1]},            wr0_23 = {sWr[ch + 2], sWr[ch + 3]};
    f32x2 wr1_01 = {sWr[64 + ch + 0], sWr[64 + ch + 1]},  wr1_23 = {sWr[64 + ch + 2], sWr[64 + ch + 3]};
    f32x2 wr2_01 = {sWr[128 + ch + 0], sWr[128 + ch + 1]}, wr2_23 = {sWr[128 + ch + 2], sWr[128 + ch + 3]};
    f32x2 wr3_01 = {sWr[192 + ch + 0], sWr[192 + ch + 1]}, wr3_23 = {sWr[192 + ch + 2], sWr[192 + ch + 3]};
    f32x2 xr01 = pk_fma_blo(Dxy, wr0_01, pk_fma_bhi(Dxy, wr1_01,
                 pk_fma_blo(Dzw, wr2_01, pk_mul_bhi(Dzw, wr3_01))));
    f32x2 xr23 = pk_fma_blo(Dxy, wr0_23, pk_fma_bhi(Dxy, wr1_23,
                 pk_fma_blo(Dzw, wr2_23, pk_mul_bhi(Dzw, wr3_23))));

    f32x2 a06_01 = {0.6f * LOG2E * satt[ch + 0], 0.6f * LOG2E * satt[ch + 1]};
    f32x2 a06_23 = {0.6f * LOG2E * satt[ch + 2], 0.6f * LOG2E * satt[ch + 3]};
    f32x2 a04_01 = {0.4f * LOG2E * satt[ch + 0], 0.4f * LOG2E * satt[ch + 1]};
    f32x2 a04_23 = {0.4f * LOG2E * satt[ch + 2], 0.4f * LOG2E * satt[ch + 3]};

    const float4* x4 = (const float4*)x;
    float ssum = 0.f;
    f32x2 accA = {0.f, 0.f}, accB = {0.f, 0.f};  // per-head sum of ev * x[src]
    for (int p = p0; p < p1; p += 32) {
        int cnt = min(32, p1 - p);
        int srcs = (ln < cnt) ? csr_src[p + ln] : 0;
        int j = 0;
        for (; j + 8 <= cnt; j += 8) {
            int s0 = __shfl(srcs, hbase + j + grp);
            int s1 = __shfl(srcs, hbase + j + 2 + grp);
            int s2 = __shfl(srcs, hbase + j + 4 + grp);
            int s3 = __shfl(srcs, hbase + j + 6 + grp);
            float4 X0 = x4[s0];
            float4 X1 = x4[s1];
            float4 X2 = x4[s2];
            float4 X3 = x4[s3];
            PROC1(X0, 0, 0)
            PROC1(X1, 0, 0)
            PROC1(X2, 0, 0)
            PROC1(X3, 0, 0)
        }
        for (; j < cnt; j += 2) {
            int idx = j + grp;
            int s0 = __shfl(srcs, hbase + (idx & 31));
            float4 X0 = x4[s0];
            PROC1(X0, idx, 1)
        }
    }
    // merge the 2 edge slots (stays within half-wave)
    float aA0 = accA.x, aA1 = accA.y, aB0 = accB.x, aB1 = accB.y;
    ssum += __shfl_xor(ssum, 16);
    aA0 += __shfl_xor(aA0, 16); aA1 += __shfl_xor(aA1, 16);
    aB0 += __shfl_xor(aB0, 16); aB1 += __shfl_xor(aB1, 16);
    // project per-head acc4 back to this lane's 4 channels
    f32x2 kA = {aA0, aA1}, kB = {aB0, aB1};
    f32x2 o01 = pk_fma_blo(kA, wl0_01, pk_fma_bhi(kA, wl1_01,
                pk_fma_blo(kB, wl2_01, pk_mul_bhi(kB, wl3_01))));
    f32x2 o23 = pk_fma_blo(kA, wl0_23, pk_fma_bhi(kA, wl1_23,
                pk_fma_blo(kB, wl2_23, pk_mul_bhi(kB, wl3_23))));
    float inv_s = (p1 > p0) ? __builtin_amdgcn_rcpf(ssum) : 0.f;
    float v0 = o01.x * inv_s + sb[ch + 0];
    float v1 = o01.y * inv_s + sb[ch + 1];
    float v2 = o23.x * inv_s + sb[ch + 2];
    float v3 = o23.y * inv_s + sb[ch + 3];
    float s4 = v0 + v1 + v2 + v3;
    s4 += __shfl_xor(s4, 1); s4 += __shfl_xor(s4, 2);
    s4 += __shfl_xor(s4, 4); s4 += __shfl_xor(s4, 8);
    float mu = s4 * (1.f / 64.f);
    float d0 = v0 - mu, d1 = v1 - mu, d2 = v2 - mu, d3 = v3 - mu;
    float q4 = d0 * d0 + d1 * d1 + d2 * d2 + d3 * d3;
    q4 += __shfl_xor(q4, 1); q4 += __shfl_xor(q4, 2);
    q4 += __shfl_xor(q4, 4); q4 += __shfl_xor(q4, 8);
    float inv = __builtin_amdgcn_rsqf(q4 * (1.f / 64.f) + 1e-5f);
    float y0 = d0 * inv * sg[ch + 0] + sbe[ch + 0];
    float y1 = d1 * inv * sg[ch + 1] + sbe[ch + 1];
    float y2 = d2 * inv * sg[ch + 2] + sbe[ch + 2];
    float y3 = d3 * inv * sg[ch + 3] + sbe[ch + 3];
    y0 = y0 > 0.f ? y0 : (ex2(y0 * LOG2E) - 1.f);
    y1 = y1 > 0.f ? y1 : (ex2(y1 * LOG2E) - 1.f);
    y2 = y2 > 0.f ? y2 : (ex2(y2 * LOG2E) - 1.f);
    y3 = y3 > 0.f ? y3 : (ex2(y3 * LOG2E) - 1.f);
    if (grp == 0) {
        *(float4*)(h + (size_t)node * 64 + ch) = make_float4(y0, y1, y2, y3);
    }
}

// ---------- layer 2 prep ----------

// xl2 (bf16) = round(h @ Wl2), xr2 (f32) = h @ Wr2
__global__ __launch_bounds__(256) void lin2_kernel(const float* __restrict__ h,
                                                   const float* __restrict__ Wl,
                                                   const float* __restrict__ Wr,
                                                   unsigned short* __restrict__ xl2b,
                                                   float* __restrict__ xr2) {
    __shared__ float sW[2 * HID * OUTC];
    __shared__ float sh[8 * HID];
    {
        const float4* wl4 = (const float4*)Wl;
        const float4* wr4 = (const float4*)Wr;
        float4* s4 = (float4*)sW;
        for (int i = threadIdx.x; i < 1024; i += 256)
            s4[i] = (i < 512) ? wl4[i] : wr4[i - 512];
    }
    int node0 = blockIdx.x * 8;
    for (int i = threadIdx.x; i < 8 * HID; i += blockDim.x) {
        int n = node0 + (i >> 6);
        sh[i] = (n < NN) ? h[n * 64 + (i & 63)] : 0.f;
    }
    __syncthreads();
    int ln = threadIdx.x >> 5;
    int col = threadIdx.x & 31;
    int node = node0 + ln;
    if (node < NN) {
        float al = 0.f, ar = 0.f;
#pragma unroll
        for (int k = 0; k < HID; k++) {
            float hv = sh[ln * 64 + k];
            al += hv * sW[k * 32 + col];
            ar += hv * sW[HID * OUTC + k * 32 + col];
        }
        xl2b[node * 32 + col] = f2bf(al);
        xr2[node * 32 + col] = ar;
    }
}

// ---------- layer 2 ----------

#define G2_PROC(RV, IDX, MASKED)                                              \
    {                                                                         \
        f32x2 L01, L23, L45, L67;                                             \
        L01.x = __uint_as_float(RV.x << 16); L01.y = __uint_as_float(RV.x & 0xFFFF0000u); \
        L23.x = __uint_as_float(RV.y << 16); L23.y = __uint_as_float(RV.y & 0xFFFF0000u); \
        L45.x = __uint_as_float(RV.z << 16); L45.y = __uint_as_float(RV.z & 0xFFFF0000u); \
        L67.x = __uint_as_float(RV.w << 16); L67.y = __uint_as_float(RV.w & 0xFFFF0000u); \
        f32x2 s01 = pk_add(L01, xr01), s23 = pk_add(L23, xr23);               \
        f32x2 s45 = pk_add(L45, xr45), s67 = pk_add(L67, xr67);               \
        f32x2 t01 = pk_abs(s01), t23 = pk_abs(s23);                           \
        f32x2 t45 = pk_abs(s45), t67 = pk_abs(s67);                           \
        f32x2 dd = pk_fma(s01, a06_01, pk_fma(t01, a04_01,                    \
                   pk_fma(s23, a06_23, pk_fma(t23, a04_23,                    \
                   pk_fma(s45, a06_45, pk_fma(t45, a04_45,                    \
                   pk_fma(s67, a06_67, pk_mul(t67, a04_67))))))));            \
        float vv = dd.x + dd.y;                                               \
        vv = quad_add_xor1(vv);                                               \
        vv = quad_add_xor2(vv);  /* 4-lane quad -> full 32-ch logit (log2) */ \
        float ev = ex2(vv);                                                   \
        if (MASKED && (IDX) >= cnt) ev = 0.f;                                 \
        ssum += ev;                                                           \
        f32x2 ev2 = {ev, ev};                                                 \
        ac01 = pk_fma(ev2, L01, ac01); ac23 = pk_fma(ev2, L23, ac23);         \
        ac45 = pk_fma(ev2, L45, ac45); ac67 = pk_fma(ev2, L67, ac67);         \
    }

// half-wave (32 lanes) per dst node; 8 edge slots (es) x 4 lanes (8 ch each)
__global__ __launch_bounds__(256) void gather2_kernel(const int* __restrict__ rowptr,
                                                      const int* __restrict__ csr_src,
                                                      const unsigned short* __restrict__ xl2b,
                                                      const float* __restrict__ xr2,
                                                      const float* __restrict__ att,
                                                      const float* __restrict__ b2,
                                                      const float* __restrict__ g2,
                                                      const float* __restrict__ be2,
                                                      float* __restrict__ out) {
    __shared__ float satt[OUTC], sb[OUTC], sg[OUTC], sbe[OUTC];
    int tid = threadIdx.x;
    if (tid < OUTC) {
        satt[tid] = att[tid];
        sb[tid] = b2[tid];
        sg[tid] = g2[tid];
        sbe[tid] = be2[tid];
    }
    __syncthreads();
    int node = blockIdx.x * 8 + (tid >> 5);  // 8 half-waves per block; grid*8 == NN
    int lane = tid & 63;
    int hbase = lane & 32;
    int ln = lane & 31;
    int es = ln >> 2;   // edge slot 0..7
    int ch = (ln & 3) * 8;
    int p0 = rowptr[node], p1 = rowptr[node + 1];

    const float* xrp = xr2 + (size_t)node * 32 + ch;
    float4 xra = *(const float4*)xrp;
    float4 xrb = *(const float4*)(xrp + 4);
    f32x2 xr01 = {xra.x, xra.y}, xr23 = {xra.z, xra.w};
    f32x2 xr45 = {xrb.x, xrb.y}, xr67 = {xrb.z, xrb.w};
    f32x2 a06_01 = {0.6f * LOG2E * satt[ch + 0], 0.6f * LOG2E * satt[ch + 1]};
    f32x2 a06_23 = {0.6f * LOG2E * satt[ch + 2], 0.6f * LOG2E * satt[ch + 3]};
    f32x2 a06_45 = {0.6f * LOG2E * satt[ch + 4], 0.6f * LOG2E * satt[ch + 5]};
    f32x2 a06_67 = {0.6f * LOG2E * satt[ch + 6], 0.6f * LOG2E * satt[ch + 7]};
    f32x2 a04_01 = {0.4f * LOG2E * satt[ch + 0], 0.4f * LOG2E * satt[ch + 1]};
    f32x2 a04_23 = {0.4f * LOG2E * satt[ch + 2], 0.4f * LOG2E * satt[ch + 3]};
    f32x2 a04_45 = {0.4f * LOG2E * satt[ch + 4], 0.4f * LOG2E * satt[ch + 5]};
    f32x2 a04_67 = {0.4f * LOG2E * satt[ch + 6], 0.4f * LOG2E * satt[ch + 7]};

    float ssum = 0.f;
    f32x2 ac01 = {0.f, 0.f}, ac23 = {0.f, 0.f}, ac45 = {0.f, 0.f}, ac67 = {0.f, 0.f};
    for (int p = p0; p < p1; p += 32) {
        int cnt = min(32, p1 - p);
        int srcs = (ln < cnt) ? csr_src[p + ln] : 0;
        int j = 0;
        for (; j + 8 <= cnt; j += 8) {
            int sa = __shfl(srcs, hbase + j + es);
            uint4 Ra = *(const uint4*)(xl2b + (size_t)sa * 32 + ch);
            G2_PROC(Ra, 0, 0)
        }
        if (j < cnt) {
            int idx = j + es;
            int sa = __shfl(srcs, hbase + (idx & 31));
            uint4 Ra = *(const uint4*)(xl2b + (size_t)sa * 32 + ch);
            G2_PROC(Ra, idx, 1)
        }
    }
    float A0 = ac01.x, A1 = ac01.y, A2 = ac23.x, A3 = ac23.y;
    float A4 = ac45.x, A5 = ac45.y, A6 = ac67.x, A7 = ac67.y;
    for (int off = 4; off < 32; off <<= 1) {  // merge 8 edge slots within half-wave
        ssum += __shfl_xor(ssum, off);
        A0 += __shfl_xor(A0, off); A1 += __shfl_xor(A1, off);
        A2 += __shfl_xor(A2, off); A3 += __shfl_xor(A3, off);
        A4 += __shfl_xor(A4, off); A5 += __shfl_xor(A5, off);
        A6 += __shfl_xor(A6, off); A7 += __shfl_xor(A7, off);
    }
    float inv_s = (p1 > p0) ? __builtin_amdgcn_rcpf(ssum) : 0.f;
    float v0 = A0 * inv_s + sb[ch + 0], v1 = A1 * inv_s + sb[ch + 1];
    float v2 = A2 * inv_s + sb[ch + 2], v3 = A3 * inv_s + sb[ch + 3];
    float v4 = A4 * inv_s + sb[ch + 4], v5 = A5 * inv_s + sb[ch + 5];
    float v6 = A6 * inv_s + sb[ch + 6], v7 = A7 * inv_s + sb[ch + 7];
    float s8 = v0 + v1 + v2 + v3 + v4 + v5 + v6 + v7;
    s8 += __shfl_xor(s8, 1); s8 += __shfl_xor(s8, 2);
    float mu = s8 * (1.f / 32.f);
    float d0 = v0 - mu, d1 = v1 - mu, d2 = v2 - mu, d3 = v3 - mu;
    float d4 = v4 - mu, d5 = v5 - mu, d6 = v6 - mu, d7 = v7 - mu;
    float q8 = d0 * d0 + d1 * d1 + d2 * d2 + d3 * d3 + d4 * d4 + d5 * d5 + d6 * d6 + d7 * d7;
    q8 += __shfl_xor(q8, 1); q8 += __shfl_xor(q8, 2);
    float inv = __builtin_amdgcn_rsqf(q8 * (1.f / 32.f) + 1e-5f);
    if (es == 0) {
        float4 oa, ob;
        oa.x = d0 * inv * sg[ch + 0] + sbe[ch + 0];
        oa.y = d1 * inv * sg[ch + 1] + sbe[ch + 1];
        oa.z = d2 * inv * sg[ch + 2] + sbe[ch + 2];
        oa.w = d3 * inv * sg[ch + 3] + sbe[ch + 3];
        ob.x = d4 * inv * sg[ch + 4] + sbe[ch + 4];
        ob.y = d5 * inv * sg[ch + 5] + sbe[ch + 5];
        ob.z = d6 * inv * sg[ch + 6] + sbe[ch + 6];
        ob.w = d7 * inv * sg[ch + 7] + sbe[ch + 7];
        *(float4*)(out + (size_t)node * 32 + ch) = oa;
        *(float4*)(out + (size_t)node * 32 + ch + 4) = ob;
    }
}

extern "C" void kernel_launch(void* const* d_in, const int* in_sizes, int n_in,
                              void* d_out, int out_size, void* d_ws, size_t ws_size,
                              hipStream_t stream) {
    const float* x    = (const float*)d_in[0];
    const int* ei     = (const int*)d_in[1];
    const float* Wl1  = (const float*)d_in[2];
    const float* Wr1  = (const float*)d_in[3];
    const float* att1 = (const float*)d_in[4];
    const float* b1   = (const float*)d_in[5];
    const float* g1   = (const float*)d_in[6];
    const float* be1  = (const float*)d_in[7];
    const float* Wl2  = (const float*)d_in[8];
    const float* Wr2  = (const float*)d_in[9];
    const float* att2 = (const float*)d_in[10];
    const float* b2   = (const float*)d_in[11];
    const float* g2   = (const float*)d_in[12];
    const float* be2  = (const float*)d_in[13];
    float* out = (float*)d_out;

    char* W = (char*)d_ws;
    float* h = (float*)W;                                    // N*64 f32 = 25.6 MB
    unsigned short* xl2b = (unsigned short*)(W + 25600000);  // N*32 bf16 = 6.4 MB
    float* xr2 = (float*)(W + 32000000);                     // N*32 f32 = 12.8 MB
    int* rowptr = (int*)(W + 44800000);                      // N+1
    int* csr_src = rowptr + NN + 1;                          // E
    unsigned int* staging = (unsigned int*)(csr_src + NE);   // NBUCK*MAXB = 8 MB
    int* gcount = (int*)(staging + (size_t)NBUCK * MAXB);    // NBUCK
    int* gbase = gcount + NBUCK;                             // NBUCK+1

    const int B = 256;

    // ---- CSR build: 3 kernels + memset ----
    hipMemsetAsync(gcount, 0, NBUCK * sizeof(int), stream);
    bucketB_kernel<<<NPB, B, 0, stream>>>(ei, gcount, staging);
    scanG_kernel<<<1, B, 0, stream>>>(gcount, gbase);
    bucketC_kernel<<<NBUCK, B, 0, stream>>>(staging, gcount, gbase, rowptr, csr_src);

    // ---- layer 1 (fused gather + LN + ELU) ----
    gather1_kernel<<<NN / 8, B, 0, stream>>>(rowptr, csr_src, x, Wl1, Wr1, att1,
                                             b1, g1, be1, h);

    // ---- layer 2 ----
    lin2_kernel<<<(NN + 7) / 8, B, 0, stream>>>(h, Wl2, Wr2, xl2b, xr2);
    gather2_kernel<<<NN / 8, B, 0, stream>>>(rowptr, csr_src, xl2b, xr2, att2,
                                             b2, g2, be2, out);
}

// Round 18
// 172.066 us; speedup vs baseline: 1.0509x; 1.0509x over previous
//
#include <hip/hip_runtime.h>
#include <math.h>

#define NN 100000
#define NE 1600000
#define HID 64
#define OUTC 32
#define NBUCK 196      // ceil(100000/512) buckets of 512 dst nodes
#define NPB 512        // partition blocks
#define EPB 3125       // edges per partition block (NPB*EPB == NE)
#define MAXB 10240     // fixed staging stride per bucket (mean 8192, sigma~90)
#define LOG2E 1.44269504088896340736f

typedef float f32x2 __attribute__((ext_vector_type(2)));

__device__ __forceinline__ f32x2 pk_mul(f32x2 a, f32x2 b) {
    f32x2 r;
    asm("v_pk_mul_f32 %0, %1, %2" : "=v"(r) : "v"(a), "v"(b));
    return r;
}
__device__ __forceinline__ f32x2 pk_fma(f32x2 a, f32x2 b, f32x2 c) {
    f32x2 r;
    asm("v_pk_fma_f32 %0, %1, %2, %3" : "=v"(r) : "v"(a), "v"(b), "v"(c));
    return r;
}
__device__ __forceinline__ f32x2 pk_add(f32x2 a, f32x2 b) {
    f32x2 r;
    asm("v_pk_add_f32 %0, %1, %2" : "=v"(r) : "v"(a), "v"(b));
    return r;
}
// broadcast lo/hi word of src0 across both halves (no movs)
__device__ __forceinline__ f32x2 pk_fma_blo(f32x2 x, f32x2 b, f32x2 c) {
    f32x2 r;
    asm("v_pk_fma_f32 %0, %1, %2, %3 op_sel:[0,0,0] op_sel_hi:[0,1,1]" : "=v"(r) : "v"(x), "v"(b), "v"(c));
    return r;
}
__device__ __forceinline__ f32x2 pk_fma_bhi(f32x2 x, f32x2 b, f32x2 c) {
    f32x2 r;
    asm("v_pk_fma_f32 %0, %1, %2, %3 op_sel:[1,0,0] op_sel_hi:[1,1,1]" : "=v"(r) : "v"(x), "v"(b), "v"(c));
    return r;
}
__device__ __forceinline__ f32x2 pk_mul_bhi(f32x2 x, f32x2 b) {
    f32x2 r;
    asm("v_pk_mul_f32 %0, %1, %2 op_sel:[1,0] op_sel_hi:[1,1]" : "=v"(r) : "v"(x), "v"(b));
    return r;
}
__device__ __forceinline__ f32x2 pk_abs(f32x2 a) {
    f32x2 r;
    r.x = __builtin_fabsf(a.x);
    r.y = __builtin_fabsf(a.y);
    return r;
}
__device__ __forceinline__ unsigned short f2bf(float f) {
    unsigned int u = __float_as_uint(f);
    u += 0x7FFFu + ((u >> 16) & 1u);
    return (unsigned short)(u >> 16);
}
// quad-level butterfly adds via DPP (VALU only, no DS)
__device__ __forceinline__ float quad_add_xor1(float v) {
    int t = __builtin_amdgcn_mov_dpp(__float_as_int(v), 0xB1, 0xF, 0xF, true);  // [1,0,3,2]
    return v + __int_as_float(t);
}
__device__ __forceinline__ float quad_add_xor2(float v) {
    int t = __builtin_amdgcn_mov_dpp(__float_as_int(v), 0x4E, 0xF, 0xF, true);  // [2,3,0,1]
    return v + __int_as_float(t);
}
__device__ __forceinline__ float ex2(float v) {  // 2^v
    float r;
    asm("v_exp_f32 %0, %1" : "=v"(r) : "v"(v));
    return r;
}

// ---------- CSR build: bucket sort with fixed-stride staging ----------

// one pass: LDS hist -> chunk reserve (global atomic per bucket) -> scatter
__global__ __launch_bounds__(256) void bucketB_kernel(const int* __restrict__ ei,
                                                      int* __restrict__ gcount,
                                                      unsigned int* __restrict__ staging) {
    __shared__ int cnt[NBUCK];
    __shared__ int cur[NBUCK];
    int tid = threadIdx.x;
    for (int i = tid; i < NBUCK; i += 256) cnt[i] = 0;
    __syncthreads();
    int base = blockIdx.x * EPB;
    const int* dstp = ei + NE;
    for (int i = tid; i < EPB; i += 256) atomicAdd(&cnt[dstp[base + i] >> 9], 1);
    __syncthreads();
    for (int i = tid; i < NBUCK; i += 256)
        cur[i] = i * MAXB + atomicAdd(&gcount[i], cnt[i]);
    __syncthreads();
    for (int i = tid; i < EPB; i += 256) {
        int d = dstp[base + i];
        int s = ei[base + i];
        int pos = atomicAdd(&cur[d >> 9], 1);
        staging[pos] = ((unsigned int)(d & 511) << 17) | (unsigned int)s;
    }
}

// per bucket: inline gbase reduce + LDS node histogram + scan -> rowptr,
// then LDS-cursor scatter -> csr_src
__global__ __launch_bounds__(256) void bucketC_kernel(const unsigned int* __restrict__ staging,
                                                      const int* __restrict__ gcount,
                                                      int* __restrict__ rowptr,
                                                      int* __restrict__ csr_src) {
    int b = blockIdx.x;
    int node0 = b << 9;
    int nnode = min(512, NN - node0);
    int tid = threadIdx.x;
    __shared__ int deg[512];
    __shared__ int sbuf[256];
    // inline exclusive prefix: e0 = sum gcount[0..b)
    int acc = (tid < b) ? gcount[tid] : 0;
    sbuf[tid] = acc;
    __syncthreads();
    for (int off = 128; off >= 1; off >>= 1) {
        if (tid < off) sbuf[tid] += sbuf[tid + off];
        __syncthreads();
    }
    int e0 = sbuf[0];
    int ecnt = gcount[b];
    const unsigned int* st = staging + (size_t)b * MAXB;
    __syncthreads();
    deg[tid] = 0;
    deg[tid + 256] = 0;
    __syncthreads();
    for (int e = tid; e < ecnt; e += 256) atomicAdd(&deg[st[e] >> 17], 1);
    __syncthreads();
    int d0 = deg[2 * tid], d1 = deg[2 * tid + 1];
    int tsum = d0 + d1;
    int run = tsum;
    sbuf[tid] = tsum;
    __syncthreads();
    for (int off = 1; off < 256; off <<= 1) {
        int u = (tid >= off) ? sbuf[tid - off] : 0;
        __syncthreads();
        run += u;
        sbuf[tid] = run;
        __syncthreads();
    }
    int eb = run - tsum;
    deg[2 * tid] = eb;
    deg[2 * tid + 1] = eb + d0;
    if (2 * tid < nnode) rowptr[node0 + 2 * tid] = e0 + eb;
    if (2 * tid + 1 < nnode) rowptr[node0 + 2 * tid + 1] = e0 + eb + d0;
    if (b == NBUCK - 1 && tid == 0) rowptr[NN] = NE;
    __syncthreads();
    for (int e = tid; e < ecnt; e += 256) {
        unsigned int p = st[e];
        int dl = p >> 17;
        int src = (int)(p & 0x1FFFFu);
        int pos = e0 + atomicAdd(&deg[dl], 1);
        csr_src[pos] = src;
    }
}

// ---------- layer 1 fused with lin2 (barrier-free, weights from L1): 2 nodes/wave ----------

#define PROC1(X, IDX, MASKED)                                                 \
    {                                                                         \
        f32x2 Xxy = {X.x, X.y}, Xzw = {X.z, X.w};                             \
        f32x2 s01 = pk_fma_blo(Xxy, wl0_01, pk_fma_bhi(Xxy, wl1_01,           \
                    pk_fma_blo(Xzw, wl2_01, pk_fma_bhi(Xzw, wl3_01, xr01)))); \
        f32x2 s23 = pk_fma_blo(Xxy, wl0_23, pk_fma_bhi(Xxy, wl1_23,           \
                    pk_fma_blo(Xzw, wl2_23, pk_fma_bhi(Xzw, wl3_23, xr23)))); \
        f32x2 t01 = pk_abs(s01), t23 = pk_abs(s23);                           \
        f32x2 dd = pk_fma(s01, a06_01, pk_fma(t01, a04_01,                    \
                   pk_fma(s23, a06_23, pk_mul(t23, a04_23))));                \
        float vv = dd.x + dd.y;                                               \
        vv = quad_add_xor1(vv);                                               \
        vv = quad_add_xor2(vv);  /* 4-lane quad -> 16-ch head logit (log2) */ \
        float ev = ex2(vv);                                                   \
        if (MASKED && (IDX) >= cnt) ev = 0.f;                                 \
        ssum += ev;                                                           \
        f32x2 ev2 = {ev, ev};                                                 \
        accA = pk_fma(ev2, Xxy, accA);                                        \
        accB = pk_fma(ev2, Xzw, accB);                                        \
    }

// half-wave (32 lanes) per dst node; per-half-wave lin2 tail reads weights from global (L1-hot).
__global__ __launch_bounds__(256) void gather1_kernel(const int* __restrict__ rowptr,
                                                      const int* __restrict__ csr_src,
                                                      const float* __restrict__ x,
                                                      const float* __restrict__ Wl,
                                                      const float* __restrict__ Wr,
                                                      const float* __restrict__ att,
                                                      const float* __restrict__ b1,
                                                      const float* __restrict__ g1,
                                                      const float* __restrict__ be1,
                                                      const float* __restrict__ Wl2,
                                                      const float* __restrict__ Wr2,
                                                      unsigned short* __restrict__ xl2b,
                                                      float* __restrict__ xr2) {
    __shared__ float sWl[4 * HID], sWr[4 * HID];
    __shared__ float satt[HID], sb[HID], sg[HID], sbe[HID];
    __shared__ float sh[8 * HID];          // 2 KB: per-half-wave h rows
    int tid = threadIdx.x;
    if (tid < 256) {
        sWl[tid] = Wl[tid];
        sWr[tid] = Wr[tid];
    }
    if (tid < HID) {
        satt[tid] = att[tid];
        sb[tid] = b1[tid];
        sg[tid] = g1[tid];
        sbe[tid] = be1[tid];
    }
    __syncthreads();
    int hw = tid >> 5;                     // half-wave 0..7
    int node = blockIdx.x * 8 + hw;        // grid*8 == NN exactly
    int lane = tid & 63;
    int hbase = lane & 32;
    int ln = lane & 31;
    int grp = ln >> 4;                     // edge slot 0..1
    int ch = (ln & 15) * 4;
    int p0 = rowptr[node], p1 = rowptr[node + 1];

    f32x2 wl0_01 = {sWl[ch + 0], sWl[ch + 1]},            wl0_23 = {sWl[ch + 2], sWl[ch + 3]};
    f32x2 wl1_01 = {sWl[64 + ch + 0], sWl[64 + ch + 1]},  wl1_23 = {sWl[64 + ch + 2], sWl[64 + ch + 3]};
    f32x2 wl2_01 = {sWl[128 + ch + 0], sWl[128 + ch + 1]}, wl2_23 = {sWl[128 + ch + 2], sWl[128 + ch + 3]};
    f32x2 wl3_01 = {sWl[192 + ch + 0], sWl[192 + ch + 1]}, wl3_23 = {sWl[192 + ch + 2], sWl[192 + ch + 3]};

    float4 xd = *(const float4*)(x + node * 4);
    f32x2 Dxy = {xd.x, xd.y}, Dzw = {xd.z, xd.w};
    f32x2 wr0_01 = {sWr[ch + 0], sWr[ch + 1]},            wr0_23 = {sWr[ch + 2], sWr[ch + 3]};
    f32x2 wr1_01 = {sWr[64 + ch + 0], sWr[64 + ch + 1]},  wr1_23 = {sWr[64 + ch + 2], sWr[64 + ch + 3]};
    f32x2 wr2_01 = {sWr[128 + ch + 0], sWr[128 + ch + 1]}, wr2_23 = {sWr[128 + ch + 2], sWr[128 + ch + 3]};
    f32x2 wr3_01 = {sWr[192 + ch + 0], sWr[192 + ch + 1]}, wr3_23 = {sWr[192 + ch + 2], sWr[192 + ch + 3]};
    f32x2 xr01 = pk_fma_blo(Dxy, wr0_01, pk_fma_bhi(Dxy, wr1_01,
                 pk_fma_blo(Dzw, wr2_01, pk_mul_bhi(Dzw, wr3_01))));
    f32x2 xr23 = pk_fma_blo(Dxy, wr0_23, pk_fma_bhi(Dxy, wr1_23,
                 pk_fma_blo(Dzw, wr2_23, pk_mul_bhi(Dzw, wr3_23))));

    f32x2 a06_01 = {0.6f * LOG2E * satt[ch + 0], 0.6f * LOG2E * satt[ch + 1]};
    f32x2 a06_23 = {0.6f * LOG2E * satt[ch + 2], 0.6f * LOG2E * satt[ch + 3]};
    f32x2 a04_01 = {0.4f * LOG2E * satt[ch + 0], 0.4f * LOG2E * satt[ch + 1]};
    f32x2 a04_23 = {0.4f * LOG2E * satt[ch + 2], 0.4f * LOG2E * satt[ch + 3]};

    const float4* x4 = (const float4*)x;
    float ssum = 0.f;
    f32x2 accA = {0.f, 0.f}, accB = {0.f, 0.f};  // per-head sum of ev * x[src]
    for (int p = p0; p < p1; p += 32) {
        int cnt = min(32, p1 - p);
        int srcs = (ln < cnt) ? csr_src[p + ln] : 0;
        int j = 0;
        for (; j + 8 <= cnt; j += 8) {
            int s0 = __shfl(srcs, hbase + j + grp);
            int s1 = __shfl(srcs, hbase + j + 2 + grp);
            int s2 = __shfl(srcs, hbase + j + 4 + grp);
            int s3 = __shfl(srcs, hbase + j + 6 + grp);
            float4 X0 = x4[s0];
            float4 X1 = x4[s1];
            float4 X2 = x4[s2];
            float4 X3 = x4[s3];
            PROC1(X0, 0, 0)
            PROC1(X1, 0, 0)
            PROC1(X2, 0, 0)
            PROC1(X3, 0, 0)
        }
        for (; j < cnt; j += 2) {
            int idx = j + grp;
            int s0 = __shfl(srcs, hbase + (idx & 31));
            float4 X0 = x4[s0];
            PROC1(X0, idx, 1)
        }
    }
    // merge the 2 edge slots (stays within half-wave)
    float aA0 = accA.x, aA1 = accA.y, aB0 = accB.x, aB1 = accB.y;
    ssum += __shfl_xor(ssum, 16);
    aA0 += __shfl_xor(aA0, 16); aA1 += __shfl_xor(aA1, 16);
    aB0 += __shfl_xor(aB0, 16); aB1 += __shfl_xor(aB1, 16);
    // project per-head acc4 back to this lane's 4 channels
    f32x2 kA = {aA0, aA1}, kB = {aB0, aB1};
    f32x2 o01 = pk_fma_blo(kA, wl0_01, pk_fma_bhi(kA, wl1_01,
                pk_fma_blo(kB, wl2_01, pk_mul_bhi(kB, wl3_01))));
    f32x2 o23 = pk_fma_blo(kA, wl0_23, pk_fma_bhi(kA, wl1_23,
                pk_fma_blo(kB, wl2_23, pk_mul_bhi(kB, wl3_23))));
    float inv_s = (p1 > p0) ? __builtin_amdgcn_rcpf(ssum) : 0.f;
    float v0 = o01.x * inv_s + sb[ch + 0];
    float v1 = o01.y * inv_s + sb[ch + 1];
    float v2 = o23.x * inv_s + sb[ch + 2];
    float v3 = o23.y * inv_s + sb[ch + 3];
    float s4v = v0 + v1 + v2 + v3;
    s4v += __shfl_xor(s4v, 1); s4v += __shfl_xor(s4v, 2);
    s4v += __shfl_xor(s4v, 4); s4v += __shfl_xor(s4v, 8);
    float mu = s4v * (1.f / 64.f);
    float d0 = v0 - mu, d1 = v1 - mu, d2 = v2 - mu, d3 = v3 - mu;
    float q4 = d0 * d0 + d1 * d1 + d2 * d2 + d3 * d3;
    q4 += __shfl_xor(q4, 1); q4 += __shfl_xor(q4, 2);
    q4 += __shfl_xor(q4, 4); q4 += __shfl_xor(q4, 8);
    float inv = __builtin_amdgcn_rsqf(q4 * (1.f / 64.f) + 1e-5f);
    float y0 = d0 * inv * sg[ch + 0] + sbe[ch + 0];
    float y1 = d1 * inv * sg[ch + 1] + sbe[ch + 1];
    float y2 = d2 * inv * sg[ch + 2] + sbe[ch + 2];
    float y3 = d3 * inv * sg[ch + 3] + sbe[ch + 3];
    y0 = y0 > 0.f ? y0 : (ex2(y0 * LOG2E) - 1.f);
    y1 = y1 > 0.f ? y1 : (ex2(y1 * LOG2E) - 1.f);
    y2 = y2 > 0.f ? y2 : (ex2(y2 * LOG2E) - 1.f);
    y3 = y3 > 0.f ? y3 : (ex2(y3 * LOG2E) - 1.f);
    if (grp == 0) {
        *(float4*)(sh + hw * 64 + ch) = make_float4(y0, y1, y2, y3);
    }
    // per-half-wave lin2 tail: h row from LDS (same-wave RAW), weights from global (L1-hot,
    // coalesced 32 consecutive floats per k). No block barrier.
    {
        int col = ln;  // 0..31
        float al = 0.f, ar = 0.f;
        const float* shp = sh + hw * 64;
#pragma unroll 16
        for (int k = 0; k < HID; k++) {
            float hv = shp[k];
            al += hv * Wl2[k * 32 + col];
            ar += hv * Wr2[k * 32 + col];
        }
        xl2b[node * 32 + col] = f2bf(al);
        xr2[node * 32 + col] = ar;
    }
}

// ---------- layer 2 ----------

#define G2_PROC(RV, IDX, MASKED)                                              \
    {                                                                         \
        f32x2 L01, L23, L45, L67;                                             \
        L01.x = __uint_as_float(RV.x << 16); L01.y = __uint_as_float(RV.x & 0xFFFF0000u); \
        L23.x = __uint_as_float(RV.y << 16); L23.y = __uint_as_float(RV.y & 0xFFFF0000u); \
        L45.x = __uint_as_float(RV.z << 16); L45.y = __uint_as_float(RV.z & 0xFFFF0000u); \
        L67.x = __uint_as_float(RV.w << 16); L67.y = __uint_as_float(RV.w & 0xFFFF0000u); \
        f32x2 s01 = pk_add(L01, xr01), s23 = pk_add(L23, xr23);               \
        f32x2 s45 = pk_add(L45, xr45), s67 = pk_add(L67, xr67);               \
        f32x2 t01 = pk_abs(s01), t23 = pk_abs(s23);                           \
        f32x2 t45 = pk_abs(s45), t67 = pk_abs(s67);                           \
        f32x2 dd = pk_fma(s01, a06_01, pk_fma(t01, a04_01,                    \
                   pk_fma(s23, a06_23, pk_fma(t23, a04_23,                    \
                   pk_fma(s45, a06_45, pk_fma(t45, a04_45,                    \
                   pk_fma(s67, a06_67, pk_mul(t67, a04_67))))))));            \
        float vv = dd.x + dd.y;                                               \
        vv = quad_add_xor1(vv);                                               \
        vv = quad_add_xor2(vv);  /* 4-lane quad -> full 32-ch logit (log2) */ \
        float ev = ex2(vv);                                                   \
        if (MASKED && (IDX) >= cnt) ev = 0.f;                                 \
        ssum += ev;                                                           \
        f32x2 ev2 = {ev, ev};                                                 \
        ac01 = pk_fma(ev2, L01, ac01); ac23 = pk_fma(ev2, L23, ac23);         \
        ac45 = pk_fma(ev2, L45, ac45); ac67 = pk_fma(ev2, L67, ac67);         \
    }

// half-wave (32 lanes) per dst node; 8 edge slots (es) x 4 lanes (8 ch each)
__global__ __launch_bounds__(256) void gather2_kernel(const int* __restrict__ rowptr,
                                                      const int* __restrict__ csr_src,
                                                      const unsigned short* __restrict__ xl2b,
                                                      const float* __restrict__ xr2,
                                                      const float* __restrict__ att,
                                                      const float* __restrict__ b2,
                                                      const float* __restrict__ g2,
                                                      const float* __restrict__ be2,
                                                      float* __restrict__ out) {
    __shared__ float satt[OUTC], sb[OUTC], sg[OUTC], sbe[OUTC];
    int tid = threadIdx.x;
    if (tid < OUTC) {
        satt[tid] = att[tid];
        sb[tid] = b2[tid];
        sg[tid] = g2[tid];
        sbe[tid] = be2[tid];
    }
    __syncthreads();
    int node = blockIdx.x * 8 + (tid >> 5);  // 8 half-waves per block; grid*8 == NN
    int lane = tid & 63;
    int hbase = lane & 32;
    int ln = lane & 31;
    int es = ln >> 2;   // edge slot 0..7
    int ch = (ln & 3) * 8;
    int p0 = rowptr[node], p1 = rowptr[node + 1];

    const float* xrp = xr2 + (size_t)node * 32 + ch;
    float4 xra = *(const float4*)xrp;
    float4 xrb = *(const float4*)(xrp + 4);
    f32x2 xr01 = {xra.x, xra.y}, xr23 = {xra.z, xra.w};
    f32x2 xr45 = {xrb.x, xrb.y}, xr67 = {xrb.z, xrb.w};
    f32x2 a06_01 = {0.6f * LOG2E * satt[ch + 0], 0.6f * LOG2E * satt[ch + 1]};
    f32x2 a06_23 = {0.6f * LOG2E * satt[ch + 2], 0.6f * LOG2E * satt[ch + 3]};
    f32x2 a06_45 = {0.6f * LOG2E * satt[ch + 4], 0.6f * LOG2E * satt[ch + 5]};
    f32x2 a06_67 = {0.6f * LOG2E * satt[ch + 6], 0.6f * LOG2E * satt[ch + 7]};
    f32x2 a04_01 = {0.4f * LOG2E * satt[ch + 0], 0.4f * LOG2E * satt[ch + 1]};
    f32x2 a04_23 = {0.4f * LOG2E * satt[ch + 2], 0.4f * LOG2E * satt[ch + 3]};
    f32x2 a04_45 = {0.4f * LOG2E * satt[ch + 4], 0.4f * LOG2E * satt[ch + 5]};
    f32x2 a04_67 = {0.4f * LOG2E * satt[ch + 6], 0.4f * LOG2E * satt[ch + 7]};

    float ssum = 0.f;
    f32x2 ac01 = {0.f, 0.f}, ac23 = {0.f, 0.f}, ac45 = {0.f, 0.f}, ac67 = {0.f, 0.f};
    for (int p = p0; p < p1; p += 32) {
        int cnt = min(32, p1 - p);
        int srcs = (ln < cnt) ? csr_src[p + ln] : 0;
        int j = 0;
        for (; j + 8 <= cnt; j += 8) {
            int sa = __shfl(srcs, hbase + j + es);
            uint4 Ra = *(const uint4*)(xl2b + (size_t)sa * 32 + ch);
            G2_PROC(Ra, 0, 0)
        }
        if (j < cnt) {
            int idx = j + es;
            int sa = __shfl(srcs, hbase + (idx & 31));
            uint4 Ra = *(const uint4*)(xl2b + (size_t)sa * 32 + ch);
            G2_PROC(Ra, idx, 1)
        }
    }
    float A0 = ac01.x, A1 = ac01.y, A2 = ac23.x, A3 = ac23.y;
    float A4 = ac45.x, A5 = ac45.y, A6 = ac67.x, A7 = ac67.y;
    for (int off = 4; off < 32; off <<= 1) {  // merge 8 edge slots within half-wave
        ssum += __shfl_xor(ssum, off);
        A0 += __shfl_xor(A0, off); A1 += __shfl_xor(A1, off);
        A2 += __shfl_xor(A2, off); A3 += __shfl_xor(A3, off);
        A4 += __shfl_xor(A4, off); A5 += __shfl_xor(A5, off);
        A6 += __shfl_xor(A6, off); A7 += __shfl_xor(A7, off);
    }
    float inv_s = (p1 > p0) ? __builtin_amdgcn_rcpf(ssum) : 0.f;
    float v0 = A0 * inv_s + sb[ch + 0], v1 = A1 * inv_s + sb[ch + 1];
    float v2 = A2 * inv_s + sb[ch + 2], v3 = A3 * inv_s + sb[ch + 3];
    float v4 = A4 * inv_s + sb[ch + 4], v5 = A5 * inv_s + sb[ch + 5];
    float v6 = A6 * inv_s + sb[ch + 6], v7 = A7 * inv_s + sb[ch + 7];
    float s8 = v0 + v1 + v2 + v3 + v4 + v5 + v6 + v7;
    s8 += __shfl_xor(s8, 1); s8 += __shfl_xor(s8, 2);
    float mu = s8 * (1.f / 32.f);
    float d0 = v0 - mu, d1 = v1 - mu, d2 = v2 - mu, d3 = v3 - mu;
    float d4 = v4 - mu, d5 = v5 - mu, d6 = v6 - mu, d7 = v7 - mu;
    float q8 = d0 * d0 + d1 * d1 + d2 * d2 + d3 * d3 + d4 * d4 + d5 * d5 + d6 * d6 + d7 * d7;
    q8 += __shfl_xor(q8, 1); q8 += __shfl_xor(q8, 2);
    float inv = __builtin_amdgcn_rsqf(q8 * (1.f / 32.f) + 1e-5f);
    if (es == 0) {
        float4 oa, ob;
        oa.x = d0 * inv * sg[ch + 0] + sbe[ch + 0];
        oa.y = d1 * inv * sg[ch + 1] + sbe[ch + 1];
        oa.z = d2 * inv * sg[ch + 2] + sbe[ch + 2];
        oa.w = d3 * inv * sg[ch + 3] + sbe[ch + 3];
        ob.x = d4 * inv * sg[ch + 4] + sbe[ch + 4];
        ob.y = d5 * inv * sg[ch + 5] + sbe[ch + 5];
        ob.z = d6 * inv * sg[ch + 6] + sbe[ch + 6];
        ob.w = d7 * inv * sg[ch + 7] + sbe[ch + 7];
        *(float4*)(out + (size_t)node * 32 + ch) = oa;
        *(float4*)(out + (size_t)node * 32 + ch + 4) = ob;
    }
}

extern "C" void kernel_launch(void* const* d_in, const int* in_sizes, int n_in,
                              void* d_out, int out_size, void* d_ws, size_t ws_size,
                              hipStream_t stream) {
    const float* x    = (const float*)d_in[0];
    const int* ei     = (const int*)d_in[1];
    const float* Wl1  = (const float*)d_in[2];
    const float* Wr1  = (const float*)d_in[3];
    const float* att1 = (const float*)d_in[4];
    const float* b1   = (const float*)d_in[5];
    const float* g1   = (const float*)d_in[6];
    const float* be1  = (const float*)d_in[7];
    const float* Wl2  = (const float*)d_in[8];
    const float* Wr2  = (const float*)d_in[9];
    const float* att2 = (const float*)d_in[10];
    const float* b2   = (const float*)d_in[11];
    const float* g2   = (const float*)d_in[12];
    const float* be2  = (const float*)d_in[13];
    float* out = (float*)d_out;

    char* W = (char*)d_ws;
    unsigned short* xl2b = (unsigned short*)W;               // N*32 bf16 = 6.4 MB
    float* xr2 = (float*)(W + 6400000);                      // N*32 f32 = 12.8 MB
    int* rowptr = (int*)(W + 19200000);                      // N+1
    int* csr_src = rowptr + NN + 1;                          // E
    unsigned int* staging = (unsigned int*)(csr_src + NE);   // NBUCK*MAXB = 8 MB
    int* gcount = (int*)(staging + (size_t)NBUCK * MAXB);    // NBUCK

    const int B = 256;

    // ---- CSR build: 2 kernels + memset ----
    hipMemsetAsync(gcount, 0, NBUCK * sizeof(int), stream);
    bucketB_kernel<<<NPB, B, 0, stream>>>(ei, gcount, staging);
    bucketC_kernel<<<NBUCK, B, 0, stream>>>(staging, gcount, rowptr, csr_src);

    // ---- layer 1 (fused gather + LN + ELU + lin2, barrier-free) ----
    gather1_kernel<<<NN / 8, B, 0, stream>>>(rowptr, csr_src, x, Wl1, Wr1, att1,
                                             b1, g1, be1, Wl2, Wr2, xl2b, xr2);

    // ---- layer 2 ----
    gather2_kernel<<<NN / 8, B, 0, stream>>>(rowptr, csr_src, xl2b, xr2, att2,
                                             b2, g2, be2, out);
}

// Round 19
// 166.789 us; speedup vs baseline: 1.0841x; 1.0316x over previous
//
#include <hip/hip_runtime.h>
#include <math.h>

#define NN 100000
#define NE 1600000
#define HID 64
#define OUTC 32
#define NBUCK 196      // ceil(100000/512) buckets of 512 dst nodes
#define NPB 512        // partition blocks
#define EPB 3125       // edges per partition block (NPB*EPB == NE)
#define MAXB 10240     // fixed staging stride per bucket (mean 8192, sigma~90)
#define LOG2E 1.44269504088896340736f

typedef float f32x2 __attribute__((ext_vector_type(2)));

__device__ __forceinline__ f32x2 pk_mul(f32x2 a, f32x2 b) {
    f32x2 r;
    asm("v_pk_mul_f32 %0, %1, %2" : "=v"(r) : "v"(a), "v"(b));
    return r;
}
__device__ __forceinline__ f32x2 pk_fma(f32x2 a, f32x2 b, f32x2 c) {
    f32x2 r;
    asm("v_pk_fma_f32 %0, %1, %2, %3" : "=v"(r) : "v"(a), "v"(b), "v"(c));
    return r;
}
__device__ __forceinline__ f32x2 pk_add(f32x2 a, f32x2 b) {
    f32x2 r;
    asm("v_pk_add_f32 %0, %1, %2" : "=v"(r) : "v"(a), "v"(b));
    return r;
}
// broadcast lo/hi word of src0 across both halves (no movs)
__device__ __forceinline__ f32x2 pk_fma_blo(f32x2 x, f32x2 b, f32x2 c) {
    f32x2 r;
    asm("v_pk_fma_f32 %0, %1, %2, %3 op_sel:[0,0,0] op_sel_hi:[0,1,1]" : "=v"(r) : "v"(x), "v"(b), "v"(c));
    return r;
}
__device__ __forceinline__ f32x2 pk_fma_bhi(f32x2 x, f32x2 b, f32x2 c) {
    f32x2 r;
    asm("v_pk_fma_f32 %0, %1, %2, %3 op_sel:[1,0,0] op_sel_hi:[1,1,1]" : "=v"(r) : "v"(x), "v"(b), "v"(c));
    return r;
}
__device__ __forceinline__ f32x2 pk_mul_bhi(f32x2 x, f32x2 b) {
    f32x2 r;
    asm("v_pk_mul_f32 %0, %1, %2 op_sel:[1,0] op_sel_hi:[1,1]" : "=v"(r) : "v"(x), "v"(b));
    return r;
}
__device__ __forceinline__ f32x2 pk_abs(f32x2 a) {
    f32x2 r;
    r.x = __builtin_fabsf(a.x);
    r.y = __builtin_fabsf(a.y);
    return r;
}
__device__ __forceinline__ unsigned short f2bf(float f) {
    unsigned int u = __float_as_uint(f);
    u += 0x7FFFu + ((u >> 16) & 1u);
    return (unsigned short)(u >> 16);
}
// quad-level butterfly adds via DPP (VALU only, no DS)
__device__ __forceinline__ float quad_add_xor1(float v) {
    int t = __builtin_amdgcn_mov_dpp(__float_as_int(v), 0xB1, 0xF, 0xF, true);  // [1,0,3,2]
    return v + __int_as_float(t);
}
__device__ __forceinline__ float quad_add_xor2(float v) {
    int t = __builtin_amdgcn_mov_dpp(__float_as_int(v), 0x4E, 0xF, 0xF, true);  // [2,3,0,1]
    return v + __int_as_float(t);
}
__device__ __forceinline__ float ex2(float v) {  // 2^v
    float r;
    asm("v_exp_f32 %0, %1" : "=v"(r) : "v"(v));
    return r;
}

// ---------- CSR build: bucket sort with fixed-stride staging ----------

// one pass: LDS hist -> chunk reserve (global atomic per bucket) -> scatter
__global__ __launch_bounds__(256) void bucketB_kernel(const int* __restrict__ ei,
                                                      int* __restrict__ gcount,
                                                      unsigned int* __restrict__ staging) {
    __shared__ int cnt[NBUCK];
    __shared__ int cur[NBUCK];
    int tid = threadIdx.x;
    for (int i = tid; i < NBUCK; i += 256) cnt[i] = 0;
    __syncthreads();
    int base = blockIdx.x * EPB;
    const int* dstp = ei + NE;
    for (int i = tid; i < EPB; i += 256) atomicAdd(&cnt[dstp[base + i] >> 9], 1);
    __syncthreads();
    for (int i = tid; i < NBUCK; i += 256)
        cur[i] = i * MAXB + atomicAdd(&gcount[i], cnt[i]);
    __syncthreads();
    for (int i = tid; i < EPB; i += 256) {
        int d = dstp[base + i];
        int s = ei[base + i];
        int pos = atomicAdd(&cur[d >> 9], 1);
        staging[pos] = ((unsigned int)(d & 511) << 17) | (unsigned int)s;
    }
}

// per bucket: inline gbase reduce + LDS node histogram + scan -> rowptr,
// then LDS-cursor scatter -> csr_src
__global__ __launch_bounds__(256) void bucketC_kernel(const unsigned int* __restrict__ staging,
                                                      const int* __restrict__ gcount,
                                                      int* __restrict__ rowptr,
                                                      int* __restrict__ csr_src) {
    int b = blockIdx.x;
    int node0 = b << 9;
    int nnode = min(512, NN - node0);
    int tid = threadIdx.x;
    __shared__ int deg[512];
    __shared__ int sbuf[256];
    // inline exclusive prefix: e0 = sum gcount[0..b)
    int acc = (tid < b) ? gcount[tid] : 0;
    sbuf[tid] = acc;
    __syncthreads();
    for (int off = 128; off >= 1; off >>= 1) {
        if (tid < off) sbuf[tid] += sbuf[tid + off];
        __syncthreads();
    }
    int e0 = sbuf[0];
    int ecnt = gcount[b];
    const unsigned int* st = staging + (size_t)b * MAXB;
    __syncthreads();
    deg[tid] = 0;
    deg[tid + 256] = 0;
    __syncthreads();
    for (int e = tid; e < ecnt; e += 256) atomicAdd(&deg[st[e] >> 17], 1);
    __syncthreads();
    int d0 = deg[2 * tid], d1 = deg[2 * tid + 1];
    int tsum = d0 + d1;
    int run = tsum;
    sbuf[tid] = tsum;
    __syncthreads();
    for (int off = 1; off < 256; off <<= 1) {
        int u = (tid >= off) ? sbuf[tid - off] : 0;
        __syncthreads();
        run += u;
        sbuf[tid] = run;
        __syncthreads();
    }
    int eb = run - tsum;
    deg[2 * tid] = eb;
    deg[2 * tid + 1] = eb + d0;
    if (2 * tid < nnode) rowptr[node0 + 2 * tid] = e0 + eb;
    if (2 * tid + 1 < nnode) rowptr[node0 + 2 * tid + 1] = e0 + eb + d0;
    if (b == NBUCK - 1 && tid == 0) rowptr[NN] = NE;
    __syncthreads();
    for (int e = tid; e < ecnt; e += 256) {
        unsigned int p = st[e];
        int dl = p >> 17;
        int src = (int)(p & 0x1FFFFu);
        int pos = e0 + atomicAdd(&deg[dl], 1);
        csr_src[pos] = src;
    }
}

// ---------- layer 1 fused with lin2 (barrier-free, interleaved LDS weights) ----------

#define PROC1(X, IDX, MASKED)                                                 \
    {                                                                         \
        f32x2 Xxy = {X.x, X.y}, Xzw = {X.z, X.w};                             \
        f32x2 s01 = pk_fma_blo(Xxy, wl0_01, pk_fma_bhi(Xxy, wl1_01,           \
                    pk_fma_blo(Xzw, wl2_01, pk_fma_bhi(Xzw, wl3_01, xr01)))); \
        f32x2 s23 = pk_fma_blo(Xxy, wl0_23, pk_fma_bhi(Xxy, wl1_23,           \
                    pk_fma_blo(Xzw, wl2_23, pk_fma_bhi(Xzw, wl3_23, xr23)))); \
        f32x2 t01 = pk_abs(s01), t23 = pk_abs(s23);                           \
        f32x2 dd = pk_fma(s01, a06_01, pk_fma(t01, a04_01,                    \
                   pk_fma(s23, a06_23, pk_mul(t23, a04_23))));                \
        float vv = dd.x + dd.y;                                               \
        vv = quad_add_xor1(vv);                                               \
        vv = quad_add_xor2(vv);  /* 4-lane quad -> 16-ch head logit (log2) */ \
        float ev = ex2(vv);                                                   \
        if (MASKED && (IDX) >= cnt) ev = 0.f;                                 \
        ssum += ev;                                                           \
        f32x2 ev2 = {ev, ev};                                                 \
        accA = pk_fma(ev2, Xxy, accA);                                        \
        accB = pk_fma(ev2, Xzw, accB);                                        \
    }

// half-wave (32 lanes) per dst node; per-half-wave lin2 tail via interleaved LDS weights.
__global__ __launch_bounds__(256) void gather1_kernel(const int* __restrict__ rowptr,
                                                      const int* __restrict__ csr_src,
                                                      const float* __restrict__ x,
                                                      const float* __restrict__ Wl,
                                                      const float* __restrict__ Wr,
                                                      const float* __restrict__ att,
                                                      const float* __restrict__ b1,
                                                      const float* __restrict__ g1,
                                                      const float* __restrict__ be1,
                                                      const float* __restrict__ Wl2,
                                                      const float* __restrict__ Wr2,
                                                      unsigned short* __restrict__ xl2b,
                                                      float* __restrict__ xr2) {
    __shared__ float sWl[4 * HID], sWr[4 * HID];
    __shared__ float satt[HID], sb[HID], sg[HID], sbe[HID];
    __shared__ f32x2 sW2i[HID * OUTC];     // 16 KB: interleaved {Wl2, Wr2} per (k,col)
    __shared__ float sh[8 * HID];          // 2 KB: per-half-wave h rows
    int tid = threadIdx.x;
    if (tid < 256) {
        sWl[tid] = Wl[tid];
        sWr[tid] = Wr[tid];
    }
    if (tid < HID) {
        satt[tid] = att[tid];
        sb[tid] = b1[tid];
        sg[tid] = g1[tid];
        sbe[tid] = be1[tid];
    }
    for (int i = tid; i < HID * OUTC; i += 256) {
        f32x2 w = {Wl2[i], Wr2[i]};
        sW2i[i] = w;
    }
    __syncthreads();
    int hw = tid >> 5;                     // half-wave 0..7
    int node = blockIdx.x * 8 + hw;        // grid*8 == NN exactly
    int lane = tid & 63;
    int hbase = lane & 32;
    int ln = lane & 31;
    int grp = ln >> 4;                     // edge slot 0..1
    int ch = (ln & 15) * 4;
    int p0 = rowptr[node], p1 = rowptr[node + 1];

    f32x2 wl0_01 = {sWl[ch + 0], sWl[ch + 1]},            wl0_23 = {sWl[ch + 2], sWl[ch + 3]};
    f32x2 wl1_01 = {sWl[64 + ch + 0], sWl[64 + ch + 1]},  wl1_23 = {sWl[64 + ch + 2], sWl[64 + ch + 3]};
    f32x2 wl2_01 = {sWl[128 + ch + 0], sWl[128 + ch + 1]}, wl2_23 = {sWl[128 + ch + 2], sWl[128 + ch + 3]};
    f32x2 wl3_01 = {sWl[192 + ch + 0], sWl[192 + ch + 1]}, wl3_23 = {sWl[192 + ch + 2], sWl[192 + ch + 3]};

    float4 xd = *(const float4*)(x + node * 4);
    f32x2 Dxy = {xd.x, xd.y}, Dzw = {xd.z, xd.w};
    f32x2 wr0_01 = {sWr[ch + 0], sWr[ch + 1]},            wr0_23 = {sWr[ch + 2], sWr[ch + 3]};
    f32x2 wr1_01 = {sWr[64 + ch + 0], sWr[64 + ch + 1]},  wr1_23 = {sWr[64 + ch + 2], sWr[64 + ch + 3]};
    f32x2 wr2_01 = {sWr[128 + ch + 0], sWr[128 + ch + 1]}, wr2_23 = {sWr[128 + ch + 2], sWr[128 + ch + 3]};
    f32x2 wr3_01 = {sWr[192 + ch + 0], sWr[192 + ch + 1]}, wr3_23 = {sWr[192 + ch + 2], sWr[192 + ch + 3]};
    f32x2 xr01 = pk_fma_blo(Dxy, wr0_01, pk_fma_bhi(Dxy, wr1_01,
                 pk_fma_blo(Dzw, wr2_01, pk_mul_bhi(Dzw, wr3_01))));
    f32x2 xr23 = pk_fma_blo(Dxy, wr0_23, pk_fma_bhi(Dxy, wr1_23,
                 pk_fma_blo(Dzw, wr2_23, pk_mul_bhi(Dzw, wr3_23))));

    f32x2 a06_01 = {0.6f * LOG2E * satt[ch + 0], 0.6f * LOG2E * satt[ch + 1]};
    f32x2 a06_23 = {0.6f * LOG2E * satt[ch + 2], 0.6f * LOG2E * satt[ch + 3]};
    f32x2 a04_01 = {0.4f * LOG2E * satt[ch + 0], 0.4f * LOG2E * satt[ch + 1]};
    f32x2 a04_23 = {0.4f * LOG2E * satt[ch + 2], 0.4f * LOG2E * satt[ch + 3]};

    const float4* x4 = (const float4*)x;
    float ssum = 0.f;
    f32x2 accA = {0.f, 0.f}, accB = {0.f, 0.f};  // per-head sum of ev * x[src]
    for (int p = p0; p < p1; p += 32) {
        int cnt = min(32, p1 - p);
        int srcs = (ln < cnt) ? csr_src[p + ln] : 0;
        int j = 0;
        for (; j + 8 <= cnt; j += 8) {
            int s0 = __shfl(srcs, hbase + j + grp);
            int s1 = __shfl(srcs, hbase + j + 2 + grp);
            int s2 = __shfl(srcs, hbase + j + 4 + grp);
            int s3 = __shfl(srcs, hbase + j + 6 + grp);
            float4 X0 = x4[s0];
            float4 X1 = x4[s1];
            float4 X2 = x4[s2];
            float4 X3 = x4[s3];
            PROC1(X0, 0, 0)
            PROC1(X1, 0, 0)
            PROC1(X2, 0, 0)
            PROC1(X3, 0, 0)
        }
        for (; j < cnt; j += 2) {
            int idx = j + grp;
            int s0 = __shfl(srcs, hbase + (idx & 31));
            float4 X0 = x4[s0];
            PROC1(X0, idx, 1)
        }
    }
    // merge the 2 edge slots (stays within half-wave)
    float aA0 = accA.x, aA1 = accA.y, aB0 = accB.x, aB1 = accB.y;
    ssum += __shfl_xor(ssum, 16);
    aA0 += __shfl_xor(aA0, 16); aA1 += __shfl_xor(aA1, 16);
    aB0 += __shfl_xor(aB0, 16); aB1 += __shfl_xor(aB1, 16);
    // project per-head acc4 back to this lane's 4 channels
    f32x2 kA = {aA0, aA1}, kB = {aB0, aB1};
    f32x2 o01 = pk_fma_blo(kA, wl0_01, pk_fma_bhi(kA, wl1_01,
                pk_fma_blo(kB, wl2_01, pk_mul_bhi(kB, wl3_01))));
    f32x2 o23 = pk_fma_blo(kA, wl0_23, pk_fma_bhi(kA, wl1_23,
                pk_fma_blo(kB, wl2_23, pk_mul_bhi(kB, wl3_23))));
    float inv_s = (p1 > p0) ? __builtin_amdgcn_rcpf(ssum) : 0.f;
    float v0 = o01.x * inv_s + sb[ch + 0];
    float v1 = o01.y * inv_s + sb[ch + 1];
    float v2 = o23.x * inv_s + sb[ch + 2];
    float v3 = o23.y * inv_s + sb[ch + 3];
    float s4v = v0 + v1 + v2 + v3;
    s4v += __shfl_xor(s4v, 1); s4v += __shfl_xor(s4v, 2);
    s4v += __shfl_xor(s4v, 4); s4v += __shfl_xor(s4v, 8);
    float mu = s4v * (1.f / 64.f);
    float d0 = v0 - mu, d1 = v1 - mu, d2 = v2 - mu, d3 = v3 - mu;
    float q4 = d0 * d0 + d1 * d1 + d2 * d2 + d3 * d3;
    q4 += __shfl_xor(q4, 1); q4 += __shfl_xor(q4, 2);
    q4 += __shfl_xor(q4, 4); q4 += __shfl_xor(q4, 8);
    float inv = __builtin_amdgcn_rsqf(q4 * (1.f / 64.f) + 1e-5f);
    float y0 = d0 * inv * sg[ch + 0] + sbe[ch + 0];
    float y1 = d1 * inv * sg[ch + 1] + sbe[ch + 1];
    float y2 = d2 * inv * sg[ch + 2] + sbe[ch + 2];
    float y3 = d3 * inv * sg[ch + 3] + sbe[ch + 3];
    y0 = y0 > 0.f ? y0 : (ex2(y0 * LOG2E) - 1.f);
    y1 = y1 > 0.f ? y1 : (ex2(y1 * LOG2E) - 1.f);
    y2 = y2 > 0.f ? y2 : (ex2(y2 * LOG2E) - 1.f);
    y3 = y3 > 0.f ? y3 : (ex2(y3 * LOG2E) - 1.f);
    if (grp == 0) {
        *(float4*)(sh + hw * 64 + ch) = make_float4(y0, y1, y2, y3);
    }
    // per-half-wave lin2 tail: packed {xl2, xr2} accumulator; h pair + 2 interleaved
    // weight b64 reads + 2 broadcast pk_fma per 2 k's. Same-wave LDS RAW (no barrier).
    {
        int col = ln;  // 0..31
        f32x2 acc = {0.f, 0.f};
        const float* shp = sh + hw * 64;
#pragma unroll 8
        for (int k = 0; k < HID; k += 2) {
            f32x2 hp = *(const f32x2*)(shp + k);
            f32x2 wk0 = sW2i[k * 32 + col];
            f32x2 wk1 = sW2i[(k + 1) * 32 + col];
            acc = pk_fma_blo(hp, wk0, acc);   // h[k]   * {wl,wr}
            acc = pk_fma_bhi(hp, wk1, acc);   // h[k+1] * {wl,wr}
        }
        xl2b[node * 32 + col] = f2bf(acc.x);
        xr2[node * 32 + col] = acc.y;
    }
}

// ---------- layer 2 ----------

#define G2_PROC(RV, IDX, MASKED)                                              \
    {                                                                         \
        f32x2 L01, L23, L45, L67;                                             \
        L01.x = __uint_as_float(RV.x << 16); L01.y = __uint_as_float(RV.x & 0xFFFF0000u); \
        L23.x = __uint_as_float(RV.y << 16); L23.y = __uint_as_float(RV.y & 0xFFFF0000u); \
        L45.x = __uint_as_float(RV.z << 16); L45.y = __uint_as_float(RV.z & 0xFFFF0000u); \
        L67.x = __uint_as_float(RV.w << 16); L67.y = __uint_as_float(RV.w & 0xFFFF0000u); \
        f32x2 s01 = pk_add(L01, xr01), s23 = pk_add(L23, xr23);               \
        f32x2 s45 = pk_add(L45, xr45), s67 = pk_add(L67, xr67);               \
        f32x2 t01 = pk_abs(s01), t23 = pk_abs(s23);                           \
        f32x2 t45 = pk_abs(s45), t67 = pk_abs(s67);                           \
        f32x2 dd = pk_fma(s01, a06_01, pk_fma(t01, a04_01,                    \
                   pk_fma(s23, a06_23, pk_fma(t23, a04_23,                    \
                   pk_fma(s45, a06_45, pk_fma(t45, a04_45,                    \
                   pk_fma(s67, a06_67, pk_mul(t67, a04_67))))))));            \
        float vv = dd.x + dd.y;                                               \
        vv = quad_add_xor1(vv);                                               \
        vv = quad_add_xor2(vv);  /* 4-lane quad -> full 32-ch logit (log2) */ \
        float ev = ex2(vv);                                                   \
        if (MASKED && (IDX) >= cnt) ev = 0.f;                                 \
        ssum += ev;                                                           \
        f32x2 ev2 = {ev, ev};                                                 \
        ac01 = pk_fma(ev2, L01, ac01); ac23 = pk_fma(ev2, L23, ac23);         \
        ac45 = pk_fma(ev2, L45, ac45); ac67 = pk_fma(ev2, L67, ac67);         \
    }

// half-wave (32 lanes) per dst node; 8 edge slots (es) x 4 lanes (8 ch each)
__global__ __launch_bounds__(256) void gather2_kernel(const int* __restrict__ rowptr,
                                                      const int* __restrict__ csr_src,
                                                      const unsigned short* __restrict__ xl2b,
                                                      const float* __restrict__ xr2,
                                                      const float* __restrict__ att,
                                                      const float* __restrict__ b2,
                                                      const float* __restrict__ g2,
                                                      const float* __restrict__ be2,
                                                      float* __restrict__ out) {
    __shared__ float satt[OUTC], sb[OUTC], sg[OUTC], sbe[OUTC];
    int tid = threadIdx.x;
    if (tid < OUTC) {
        satt[tid] = att[tid];
        sb[tid] = b2[tid];
        sg[tid] = g2[tid];
        sbe[tid] = be2[tid];
    }
    __syncthreads();
    int node = blockIdx.x * 8 + (tid >> 5);  // 8 half-waves per block; grid*8 == NN
    int lane = tid & 63;
    int hbase = lane & 32;
    int ln = lane & 31;
    int es = ln >> 2;   // edge slot 0..7
    int ch = (ln & 3) * 8;
    int p0 = rowptr[node], p1 = rowptr[node + 1];

    const float* xrp = xr2 + (size_t)node * 32 + ch;
    float4 xra = *(const float4*)xrp;
    float4 xrb = *(const float4*)(xrp + 4);
    f32x2 xr01 = {xra.x, xra.y}, xr23 = {xra.z, xra.w};
    f32x2 xr45 = {xrb.x, xrb.y}, xr67 = {xrb.z, xrb.w};
    f32x2 a06_01 = {0.6f * LOG2E * satt[ch + 0], 0.6f * LOG2E * satt[ch + 1]};
    f32x2 a06_23 = {0.6f * LOG2E * satt[ch + 2], 0.6f * LOG2E * satt[ch + 3]};
    f32x2 a06_45 = {0.6f * LOG2E * satt[ch + 4], 0.6f * LOG2E * satt[ch + 5]};
    f32x2 a06_67 = {0.6f * LOG2E * satt[ch + 6], 0.6f * LOG2E * satt[ch + 7]};
    f32x2 a04_01 = {0.4f * LOG2E * satt[ch + 0], 0.4f * LOG2E * satt[ch + 1]};
    f32x2 a04_23 = {0.4f * LOG2E * satt[ch + 2], 0.4f * LOG2E * satt[ch + 3]};
    f32x2 a04_45 = {0.4f * LOG2E * satt[ch + 4], 0.4f * LOG2E * satt[ch + 5]};
    f32x2 a04_67 = {0.4f * LOG2E * satt[ch + 6], 0.4f * LOG2E * satt[ch + 7]};

    float ssum = 0.f;
    f32x2 ac01 = {0.f, 0.f}, ac23 = {0.f, 0.f}, ac45 = {0.f, 0.f}, ac67 = {0.f, 0.f};
    for (int p = p0; p < p1; p += 32) {
        int cnt = min(32, p1 - p);
        int srcs = (ln < cnt) ? csr_src[p + ln] : 0;
        int j = 0;
        for (; j + 8 <= cnt; j += 8) {
            int sa = __shfl(srcs, hbase + j + es);
            uint4 Ra = *(const uint4*)(xl2b + (size_t)sa * 32 + ch);
            G2_PROC(Ra, 0, 0)
        }
        if (j < cnt) {
            int idx = j + es;
            int sa = __shfl(srcs, hbase + (idx & 31));
            uint4 Ra = *(const uint4*)(xl2b + (size_t)sa * 32 + ch);
            G2_PROC(Ra, idx, 1)
        }
    }
    float A0 = ac01.x, A1 = ac01.y, A2 = ac23.x, A3 = ac23.y;
    float A4 = ac45.x, A5 = ac45.y, A6 = ac67.x, A7 = ac67.y;
    for (int off = 4; off < 32; off <<= 1) {  // merge 8 edge slots within half-wave
        ssum += __shfl_xor(ssum, off);
        A0 += __shfl_xor(A0, off); A1 += __shfl_xor(A1, off);
        A2 += __shfl_xor(A2, off); A3 += __shfl_xor(A3, off);
        A4 += __shfl_xor(A4, off); A5 += __shfl_xor(A5, off);
        A6 += __shfl_xor(A6, off); A7 += __shfl_xor(A7, off);
    }
    float inv_s = (p1 > p0) ? __builtin_amdgcn_rcpf(ssum) : 0.f;
    float v0 = A0 * inv_s + sb[ch + 0], v1 = A1 * inv_s + sb[ch + 1];
    float v2 = A2 * inv_s + sb[ch + 2], v3 = A3 * inv_s + sb[ch + 3];
    float v4 = A4 * inv_s + sb[ch + 4], v5 = A5 * inv_s + sb[ch + 5];
    float v6 = A6 * inv_s + sb[ch + 6], v7 = A7 * inv_s + sb[ch + 7];
    float s8 = v0 + v1 + v2 + v3 + v4 + v5 + v6 + v7;
    s8 += __shfl_xor(s8, 1); s8 += __shfl_xor(s8, 2);
    float mu = s8 * (1.f / 32.f);
    float d0 = v0 - mu, d1 = v1 - mu, d2 = v2 - mu, d3 = v3 - mu;
    float d4 = v4 - mu, d5 = v5 - mu, d6 = v6 - mu, d7 = v7 - mu;
    float q8 = d0 * d0 + d1 * d1 + d2 * d2 + d3 * d3 + d4 * d4 + d5 * d5 + d6 * d6 + d7 * d7;
    q8 += __shfl_xor(q8, 1); q8 += __shfl_xor(q8, 2);
    float inv = __builtin_amdgcn_rsqf(q8 * (1.f / 32.f) + 1e-5f);
    if (es == 0) {
        float4 oa, ob;
        oa.x = d0 * inv * sg[ch + 0] + sbe[ch + 0];
        oa.y = d1 * inv * sg[ch + 1] + sbe[ch + 1];
        oa.z = d2 * inv * sg[ch + 2] + sbe[ch + 2];
        oa.w = d3 * inv * sg[ch + 3] + sbe[ch + 3];
        ob.x = d4 * inv * sg[ch + 4] + sbe[ch + 4];
        ob.y = d5 * inv * sg[ch + 5] + sbe[ch + 5];
        ob.z = d6 * inv * sg[ch + 6] + sbe[ch + 6];
        ob.w = d7 * inv * sg[ch + 7] + sbe[ch + 7];
        *(float4*)(out + (size_t)node * 32 + ch) = oa;
        *(float4*)(out + (size_t)node * 32 + ch + 4) = ob;
    }
}

extern "C" void kernel_launch(void* const* d_in, const int* in_sizes, int n_in,
                              void* d_out, int out_size, void* d_ws, size_t ws_size,
                              hipStream_t stream) {
    const float* x    = (const float*)d_in[0];
    const int* ei     = (const int*)d_in[1];
    const float* Wl1  = (const float*)d_in[2];
    const float* Wr1  = (const float*)d_in[3];
    const float* att1 = (const float*)d_in[4];
    const float* b1   = (const float*)d_in[5];
    const float* g1   = (const float*)d_in[6];
    const float* be1  = (const float*)d_in[7];
    const float* Wl2  = (const float*)d_in[8];
    const float* Wr2  = (const float*)d_in[9];
    const float* att2 = (const float*)d_in[10];
    const float* b2   = (const float*)d_in[11];
    const float* g2   = (const float*)d_in[12];
    const float* be2  = (const float*)d_in[13];
    float* out = (float*)d_out;

    char* W = (char*)d_ws;
    unsigned short* xl2b = (unsigned short*)W;               // N*32 bf16 = 6.4 MB
    float* xr2 = (float*)(W + 6400000);                      // N*32 f32 = 12.8 MB
    int* rowptr = (int*)(W + 19200000);                      // N+1
    int* csr_src = rowptr + NN + 1;                          // E
    unsigned int* staging = (unsigned int*)(csr_src + NE);   // NBUCK*MAXB = 8 MB
    int* gcount = (int*)(staging + (size_t)NBUCK * MAXB);    // NBUCK

    const int B = 256;

    // ---- CSR build: 2 kernels + memset ----
    hipMemsetAsync(gcount, 0, NBUCK * sizeof(int), stream);
    bucketB_kernel<<<NPB, B, 0, stream>>>(ei, gcount, staging);
    bucketC_kernel<<<NBUCK, B, 0, stream>>>(staging, gcount, rowptr, csr_src);

    // ---- layer 1 (fused gather + LN + ELU + lin2, barrier-free) ----
    gather1_kernel<<<NN / 8, B, 0, stream>>>(rowptr, csr_src, x, Wl1, Wr1, att1,
                                             b1, g1, be1, Wl2, Wr2, xl2b, xr2);

    // ---- layer 2 ----
    gather2_kernel<<<NN / 8, B, 0, stream>>>(rowptr, csr_src, xl2b, xr2, att2,
                                             b2, g2, be2, out);
}

// Round 20
// 162.374 us; speedup vs baseline: 1.1136x; 1.0272x over previous
//
#include <hip/hip_runtime.h>
#include <math.h>

#define NN 100000
#define NE 1600000
#define HID 64
#define OUTC 32
#define NBUCK 196      // ceil(100000/512) buckets of 512 dst nodes
#define NPB 512        // partition blocks
#define EPB 3125       // edges per partition block (NPB*EPB == NE)
#define MAXB 10240     // fixed staging stride per bucket (mean 8192, sigma~90)
#define LOG2E 1.44269504088896340736f

typedef float f32x2 __attribute__((ext_vector_type(2)));

__device__ __forceinline__ f32x2 pk_mul(f32x2 a, f32x2 b) {
    f32x2 r;
    asm("v_pk_mul_f32 %0, %1, %2" : "=v"(r) : "v"(a), "v"(b));
    return r;
}
__device__ __forceinline__ f32x2 pk_fma(f32x2 a, f32x2 b, f32x2 c) {
    f32x2 r;
    asm("v_pk_fma_f32 %0, %1, %2, %3" : "=v"(r) : "v"(a), "v"(b), "v"(c));
    return r;
}
__device__ __forceinline__ f32x2 pk_add(f32x2 a, f32x2 b) {
    f32x2 r;
    asm("v_pk_add_f32 %0, %1, %2" : "=v"(r) : "v"(a), "v"(b));
    return r;
}
// broadcast lo/hi word of src0 across both halves (no movs)
__device__ __forceinline__ f32x2 pk_fma_blo(f32x2 x, f32x2 b, f32x2 c) {
    f32x2 r;
    asm("v_pk_fma_f32 %0, %1, %2, %3 op_sel:[0,0,0] op_sel_hi:[0,1,1]" : "=v"(r) : "v"(x), "v"(b), "v"(c));
    return r;
}
__device__ __forceinline__ f32x2 pk_fma_bhi(f32x2 x, f32x2 b, f32x2 c) {
    f32x2 r;
    asm("v_pk_fma_f32 %0, %1, %2, %3 op_sel:[1,0,0] op_sel_hi:[1,1,1]" : "=v"(r) : "v"(x), "v"(b), "v"(c));
    return r;
}
__device__ __forceinline__ f32x2 pk_mul_bhi(f32x2 x, f32x2 b) {
    f32x2 r;
    asm("v_pk_mul_f32 %0, %1, %2 op_sel:[1,0] op_sel_hi:[1,1]" : "=v"(r) : "v"(x), "v"(b));
    return r;
}
__device__ __forceinline__ f32x2 pk_abs(f32x2 a) {
    f32x2 r;
    r.x = __builtin_fabsf(a.x);
    r.y = __builtin_fabsf(a.y);
    return r;
}
__device__ __forceinline__ unsigned short f2bf(float f) {
    unsigned int u = __float_as_uint(f);
    u += 0x7FFFu + ((u >> 16) & 1u);
    return (unsigned short)(u >> 16);
}
// quad-level butterfly adds via DPP (VALU only, no DS)
__device__ __forceinline__ float quad_add_xor1(float v) {
    int t = __builtin_amdgcn_mov_dpp(__float_as_int(v), 0xB1, 0xF, 0xF, true);  // [1,0,3,2]
    return v + __int_as_float(t);
}
__device__ __forceinline__ float quad_add_xor2(float v) {
    int t = __builtin_amdgcn_mov_dpp(__float_as_int(v), 0x4E, 0xF, 0xF, true);  // [2,3,0,1]
    return v + __int_as_float(t);
}
__device__ __forceinline__ float ex2(float v) {  // 2^v
    float r;
    asm("v_exp_f32 %0, %1" : "=v"(r) : "v"(v));
    return r;
}

// ---------- CSR build: bucket sort with fixed-stride staging (2 kernels) ----------

// one pass: LDS hist -> chunk reserve (global atomic per bucket) -> scatter
__global__ __launch_bounds__(256) void bucketB_kernel(const int* __restrict__ ei,
                                                      int* __restrict__ gcount,
                                                      unsigned int* __restrict__ staging) {
    __shared__ int cnt[NBUCK];
    __shared__ int cur[NBUCK];
    int tid = threadIdx.x;
    for (int i = tid; i < NBUCK; i += 256) cnt[i] = 0;
    __syncthreads();
    int base = blockIdx.x * EPB;
    const int* dstp = ei + NE;
    for (int i = tid; i < EPB; i += 256) atomicAdd(&cnt[dstp[base + i] >> 9], 1);
    __syncthreads();
    for (int i = tid; i < NBUCK; i += 256)
        cur[i] = i * MAXB + atomicAdd(&gcount[i], cnt[i]);
    __syncthreads();
    for (int i = tid; i < EPB; i += 256) {
        int d = dstp[base + i];
        int s = ei[base + i];
        int pos = atomicAdd(&cur[d >> 9], 1);
        staging[pos] = ((unsigned int)(d & 511) << 17) | (unsigned int)s;
    }
}

// per bucket: inline gbase reduce + LDS node histogram + scan -> rowptr,
// then LDS-cursor scatter -> csr_src
__global__ __launch_bounds__(256) void bucketC_kernel(const unsigned int* __restrict__ staging,
                                                      const int* __restrict__ gcount,
                                                      int* __restrict__ rowptr,
                                                      int* __restrict__ csr_src) {
    int b = blockIdx.x;
    int node0 = b << 9;
    int nnode = min(512, NN - node0);
    int tid = threadIdx.x;
    __shared__ int deg[512];
    __shared__ int sbuf[256];
    // inline exclusive prefix: e0 = sum gcount[0..b)
    int acc = (tid < b) ? gcount[tid] : 0;
    sbuf[tid] = acc;
    __syncthreads();
    for (int off = 128; off >= 1; off >>= 1) {
        if (tid < off) sbuf[tid] += sbuf[tid + off];
        __syncthreads();
    }
    int e0 = sbuf[0];
    int ecnt = gcount[b];
    const unsigned int* st = staging + (size_t)b * MAXB;
    __syncthreads();
    deg[tid] = 0;
    deg[tid + 256] = 0;
    __syncthreads();
    for (int e = tid; e < ecnt; e += 256) atomicAdd(&deg[st[e] >> 17], 1);
    __syncthreads();
    int d0 = deg[2 * tid], d1 = deg[2 * tid + 1];
    int tsum = d0 + d1;
    int run = tsum;
    sbuf[tid] = tsum;
    __syncthreads();
    for (int off = 1; off < 256; off <<= 1) {
        int u = (tid >= off) ? sbuf[tid - off] : 0;
        __syncthreads();
        run += u;
        sbuf[tid] = run;
        __syncthreads();
    }
    int eb = run - tsum;
    deg[2 * tid] = eb;
    deg[2 * tid + 1] = eb + d0;
    if (2 * tid < nnode) rowptr[node0 + 2 * tid] = e0 + eb;
    if (2 * tid + 1 < nnode) rowptr[node0 + 2 * tid + 1] = e0 + eb + d0;
    if (b == NBUCK - 1 && tid == 0) rowptr[NN] = NE;
    __syncthreads();
    for (int e = tid; e < ecnt; e += 256) {
        unsigned int p = st[e];
        int dl = p >> 17;
        int src = (int)(p & 0x1FFFFu);
        int pos = e0 + atomicAdd(&deg[dl], 1);
        csr_src[pos] = src;
    }
}

// ---------- layer 1 fused with lin2 (barrier-free): 2 nodes/wave ----------

#define PROC1(X, IDX, MASKED)                                                 \
    {                                                                         \
        f32x2 Xxy = {X.x, X.y}, Xzw = {X.z, X.w};                             \
        f32x2 s01 = pk_fma_blo(Xxy, wl0_01, pk_fma_bhi(Xxy, wl1_01,           \
                    pk_fma_blo(Xzw, wl2_01, pk_fma_bhi(Xzw, wl3_01, xr01)))); \
        f32x2 s23 = pk_fma_blo(Xxy, wl0_23, pk_fma_bhi(Xxy, wl1_23,           \
                    pk_fma_blo(Xzw, wl2_23, pk_fma_bhi(Xzw, wl3_23, xr23)))); \
        f32x2 t01 = pk_abs(s01), t23 = pk_abs(s23);                           \
        f32x2 dd = pk_fma(s01, a06_01, pk_fma(t01, a04_01,                    \
                   pk_fma(s23, a06_23, pk_mul(t23, a04_23))));                \
        float vv = dd.x + dd.y;                                               \
        vv = quad_add_xor1(vv);                                               \
        vv = quad_add_xor2(vv);  /* 4-lane quad -> 16-ch head logit (log2) */ \
        float ev = ex2(vv);                                                   \
        if (MASKED && (IDX) >= cnt) ev = 0.f;                                 \
        ssum += ev;                                                           \
        f32x2 ev2 = {ev, ev};                                                 \
        accA = pk_fma(ev2, Xxy, accA);                                        \
        accB = pk_fma(ev2, Xzw, accB);                                        \
    }

// half-wave (32 lanes) per dst node; per-half-wave lin2 (no post-gather barrier).
__global__ __launch_bounds__(256) void gather1_kernel(const int* __restrict__ rowptr,
                                                      const int* __restrict__ csr_src,
                                                      const float* __restrict__ x,
                                                      const float* __restrict__ Wl,
                                                      const float* __restrict__ Wr,
                                                      const float* __restrict__ att,
                                                      const float* __restrict__ b1,
                                                      const float* __restrict__ g1,
                                                      const float* __restrict__ be1,
                                                      const float* __restrict__ Wl2,
                                                      const float* __restrict__ Wr2,
                                                      unsigned short* __restrict__ xl2b,
                                                      float* __restrict__ xr2) {
    __shared__ float sWl[4 * HID], sWr[4 * HID];
    __shared__ float satt[HID], sb[HID], sg[HID], sbe[HID];
    __shared__ float sW2[2 * HID * OUTC];  // 16 KB: Wl2 then Wr2
    __shared__ float sh[8 * HID];          // 2 KB: per-half-wave h rows
    int tid = threadIdx.x;
    if (tid < 256) {
        sWl[tid] = Wl[tid];
        sWr[tid] = Wr[tid];
    }
    if (tid < HID) {
        satt[tid] = att[tid];
        sb[tid] = b1[tid];
        sg[tid] = g1[tid];
        sbe[tid] = be1[tid];
    }
    {  // vectorized weight staging: 1024 float4s over 256 threads
        const float4* wl4 = (const float4*)Wl2;
        const float4* wr4 = (const float4*)Wr2;
        float4* s4 = (float4*)sW2;
        for (int i = tid; i < 1024; i += 256)
            s4[i] = (i < 512) ? wl4[i] : wr4[i - 512];
    }
    __syncthreads();
    int hw = tid >> 5;                     // half-wave 0..7
    int node = blockIdx.x * 8 + hw;        // grid*8 == NN exactly
    int lane = tid & 63;
    int hbase = lane & 32;
    int ln = lane & 31;
    int grp = ln >> 4;                     // edge slot 0..1
    int ch = (ln & 15) * 4;
    int p0 = rowptr[node], p1 = rowptr[node + 1];

    f32x2 wl0_01 = {sWl[ch + 0], sWl[ch + 1]},            wl0_23 = {sWl[ch + 2], sWl[ch + 3]};
    f32x2 wl1_01 = {sWl[64 + ch + 0], sWl[64 + ch + 1]},  wl1_23 = {sWl[64 + ch + 2], sWl[64 + ch + 3]};
    f32x2 wl2_01 = {sWl[128 + ch + 0], sWl[128 + ch + 1]}, wl2_23 = {sWl[128 + ch + 2], sWl[128 + ch + 3]};
    f32x2 wl3_01 = {sWl[192 + ch + 0], sWl[192 + ch + 1]}, wl3_23 = {sWl[192 + ch + 2], sWl[192 + ch + 3]};

    float4 xd = *(const float4*)(x + node * 4);
    f32x2 Dxy = {xd.x, xd.y}, Dzw = {xd.z, xd.w};
    f32x2 wr0_01 = {sWr[ch + 0], sWr[ch + 1]},            wr0_23 = {sWr[ch + 2], sWr[ch + 3]};
    f32x2 wr1_01 = {sWr[64 + ch + 0], sWr[64 + ch + 1]},  wr1_23 = {sWr[64 + ch + 2], sWr[64 + ch + 3]};
    f32x2 wr2_01 = {sWr[128 + ch + 0], sWr[128 + ch + 1]}, wr2_23 = {sWr[128 + ch + 2], sWr[128 + ch + 3]};
    f32x2 wr3_01 = {sWr[192 + ch + 0], sWr[192 + ch + 1]}, wr3_23 = {sWr[192 + ch + 2], sWr[192 + ch + 3]};
    f32x2 xr01 = pk_fma_blo(Dxy, wr0_01, pk_fma_bhi(Dxy, wr1_01,
                 pk_fma_blo(Dzw, wr2_01, pk_mul_bhi(Dzw, wr3_01))));
    f32x2 xr23 = pk_fma_blo(Dxy, wr0_23, pk_fma_bhi(Dxy, wr1_23,
                 pk_fma_blo(Dzw, wr2_23, pk_mul_bhi(Dzw, wr3_23))));

    f32x2 a06_01 = {0.6f * LOG2E * satt[ch + 0], 0.6f * LOG2E * satt[ch + 1]};
    f32x2 a06_23 = {0.6f * LOG2E * satt[ch + 2], 0.6f * LOG2E * satt[ch + 3]};
    f32x2 a04_01 = {0.4f * LOG2E * satt[ch + 0], 0.4f * LOG2E * satt[ch + 1]};
    f32x2 a04_23 = {0.4f * LOG2E * satt[ch + 2], 0.4f * LOG2E * satt[ch + 3]};

    const float4* x4 = (const float4*)x;
    float ssum = 0.f;
    f32x2 accA = {0.f, 0.f}, accB = {0.f, 0.f};  // per-head sum of ev * x[src]
    for (int p = p0; p < p1; p += 32) {
        int cnt = min(32, p1 - p);
        int srcs = (ln < cnt) ? csr_src[p + ln] : 0;
        int j = 0;
        for (; j + 8 <= cnt; j += 8) {
            int s0 = __shfl(srcs, hbase + j + grp);
            int s1 = __shfl(srcs, hbase + j + 2 + grp);
            int s2 = __shfl(srcs, hbase + j + 4 + grp);
            int s3 = __shfl(srcs, hbase + j + 6 + grp);
            float4 X0 = x4[s0];
            float4 X1 = x4[s1];
            float4 X2 = x4[s2];
            float4 X3 = x4[s3];
            PROC1(X0, 0, 0)
            PROC1(X1, 0, 0)
            PROC1(X2, 0, 0)
            PROC1(X3, 0, 0)
        }
        for (; j < cnt; j += 2) {
            int idx = j + grp;
            int s0 = __shfl(srcs, hbase + (idx & 31));
            float4 X0 = x4[s0];
            PROC1(X0, idx, 1)
        }
    }
    // merge the 2 edge slots (stays within half-wave)
    float aA0 = accA.x, aA1 = accA.y, aB0 = accB.x, aB1 = accB.y;
    ssum += __shfl_xor(ssum, 16);
    aA0 += __shfl_xor(aA0, 16); aA1 += __shfl_xor(aA1, 16);
    aB0 += __shfl_xor(aB0, 16); aB1 += __shfl_xor(aB1, 16);
    // project per-head acc4 back to this lane's 4 channels
    f32x2 kA = {aA0, aA1}, kB = {aB0, aB1};
    f32x2 o01 = pk_fma_blo(kA, wl0_01, pk_fma_bhi(kA, wl1_01,
                pk_fma_blo(kB, wl2_01, pk_mul_bhi(kB, wl3_01))));
    f32x2 o23 = pk_fma_blo(kA, wl0_23, pk_fma_bhi(kA, wl1_23,
                pk_fma_blo(kB, wl2_23, pk_mul_bhi(kB, wl3_23))));
    float inv_s = (p1 > p0) ? __builtin_amdgcn_rcpf(ssum) : 0.f;
    float v0 = o01.x * inv_s + sb[ch + 0];
    float v1 = o01.y * inv_s + sb[ch + 1];
    float v2 = o23.x * inv_s + sb[ch + 2];
    float v3 = o23.y * inv_s + sb[ch + 3];
    float s4v = v0 + v1 + v2 + v3;
    s4v += __shfl_xor(s4v, 1); s4v += __shfl_xor(s4v, 2);
    s4v += __shfl_xor(s4v, 4); s4v += __shfl_xor(s4v, 8);
    float mu = s4v * (1.f / 64.f);
    float d0 = v0 - mu, d1 = v1 - mu, d2 = v2 - mu, d3 = v3 - mu;
    float q4 = d0 * d0 + d1 * d1 + d2 * d2 + d3 * d3;
    q4 += __shfl_xor(q4, 1); q4 += __shfl_xor(q4, 2);
    q4 += __shfl_xor(q4, 4); q4 += __shfl_xor(q4, 8);
    float inv = __builtin_amdgcn_rsqf(q4 * (1.f / 64.f) + 1e-5f);
    float y0 = d0 * inv * sg[ch + 0] + sbe[ch + 0];
    float y1 = d1 * inv * sg[ch + 1] + sbe[ch + 1];
    float y2 = d2 * inv * sg[ch + 2] + sbe[ch + 2];
    float y3 = d3 * inv * sg[ch + 3] + sbe[ch + 3];
    y0 = y0 > 0.f ? y0 : (ex2(y0 * LOG2E) - 1.f);
    y1 = y1 > 0.f ? y1 : (ex2(y1 * LOG2E) - 1.f);
    y2 = y2 > 0.f ? y2 : (ex2(y2 * LOG2E) - 1.f);
    y3 = y3 > 0.f ? y3 : (ex2(y3 * LOG2E) - 1.f);
    if (grp == 0) {
        *(float4*)(sh + hw * 64 + ch) = make_float4(y0, y1, y2, y3);
    }
    // per-half-wave lin2: slot written & read by THIS half-wave only (same wave ->
    // LDS RAW handled by lgkmcnt; no block barrier, no node coupling).
    {
        int col = ln;  // 0..31
        float al = 0.f, ar = 0.f;
        const float* shp = sh + hw * 64;
#pragma unroll
        for (int k = 0; k < HID; k++) {
            float hv = shp[k];
            al += hv * sW2[k * 32 + col];
            ar += hv * sW2[HID * OUTC + k * 32 + col];
        }
        xl2b[node * 32 + col] = f2bf(al);
        xr2[node * 32 + col] = ar;
    }
}

// ---------- layer 2 ----------

#define G2_PROC(RV, IDX, MASKED)                                              \
    {                                                                         \
        f32x2 L01, L23, L45, L67;                                             \
        L01.x = __uint_as_float(RV.x << 16); L01.y = __uint_as_float(RV.x & 0xFFFF0000u); \
        L23.x = __uint_as_float(RV.y << 16); L23.y = __uint_as_float(RV.y & 0xFFFF0000u); \
        L45.x = __uint_as_float(RV.z << 16); L45.y = __uint_as_float(RV.z & 0xFFFF0000u); \
        L67.x = __uint_as_float(RV.w << 16); L67.y = __uint_as_float(RV.w & 0xFFFF0000u); \
        f32x2 s01 = pk_add(L01, xr01), s23 = pk_add(L23, xr23);               \
        f32x2 s45 = pk_add(L45, xr45), s67 = pk_add(L67, xr67);               \
        f32x2 t01 = pk_abs(s01), t23 = pk_abs(s23);                           \
        f32x2 t45 = pk_abs(s45), t67 = pk_abs(s67);                           \
        f32x2 dd = pk_fma(s01, a06_01, pk_fma(t01, a04_01,                    \
                   pk_fma(s23, a06_23, pk_fma(t23, a04_23,                    \
                   pk_fma(s45, a06_45, pk_fma(t45, a04_45,                    \
                   pk_fma(s67, a06_67, pk_mul(t67, a04_67))))))));            \
        float vv = dd.x + dd.y;                                               \
        vv = quad_add_xor1(vv);                                               \
        vv = quad_add_xor2(vv);  /* 4-lane quad -> full 32-ch logit (log2) */ \
        float ev = ex2(vv);                                                   \
        if (MASKED && (IDX) >= cnt) ev = 0.f;                                 \
        ssum += ev;                                                           \
        f32x2 ev2 = {ev, ev};                                                 \
        ac01 = pk_fma(ev2, L01, ac01); ac23 = pk_fma(ev2, L23, ac23);         \
        ac45 = pk_fma(ev2, L45, ac45); ac67 = pk_fma(ev2, L67, ac67);         \
    }

// half-wave (32 lanes) per dst node; 8 edge slots (es) x 4 lanes (8 ch each)
__global__ __launch_bounds__(256) void gather2_kernel(const int* __restrict__ rowptr,
                                                      const int* __restrict__ csr_src,
                                                      const unsigned short* __restrict__ xl2b,
                                                      const float* __restrict__ xr2,
                                                      const float* __restrict__ att,
                                                      const float* __restrict__ b2,
                                                      const float* __restrict__ g2,
                                                      const float* __restrict__ be2,
                                                      float* __restrict__ out) {
    __shared__ float satt[OUTC], sb[OUTC], sg[OUTC], sbe[OUTC];
    int tid = threadIdx.x;
    if (tid < OUTC) {
        satt[tid] = att[tid];
        sb[tid] = b2[tid];
        sg[tid] = g2[tid];
        sbe[tid] = be2[tid];
    }
    __syncthreads();
    int node = blockIdx.x * 8 + (tid >> 5);  // 8 half-waves per block; grid*8 == NN
    int lane = tid & 63;
    int hbase = lane & 32;
    int ln = lane & 31;
    int es = ln >> 2;   // edge slot 0..7
    int ch = (ln & 3) * 8;
    int p0 = rowptr[node], p1 = rowptr[node + 1];

    const float* xrp = xr2 + (size_t)node * 32 + ch;
    float4 xra = *(const float4*)xrp;
    float4 xrb = *(const float4*)(xrp + 4);
    f32x2 xr01 = {xra.x, xra.y}, xr23 = {xra.z, xra.w};
    f32x2 xr45 = {xrb.x, xrb.y}, xr67 = {xrb.z, xrb.w};
    f32x2 a06_01 = {0.6f * LOG2E * satt[ch + 0], 0.6f * LOG2E * satt[ch + 1]};
    f32x2 a06_23 = {0.6f * LOG2E * satt[ch + 2], 0.6f * LOG2E * satt[ch + 3]};
    f32x2 a06_45 = {0.6f * LOG2E * satt[ch + 4], 0.6f * LOG2E * satt[ch + 5]};
    f32x2 a06_67 = {0.6f * LOG2E * satt[ch + 6], 0.6f * LOG2E * satt[ch + 7]};
    f32x2 a04_01 = {0.4f * LOG2E * satt[ch + 0], 0.4f * LOG2E * satt[ch + 1]};
    f32x2 a04_23 = {0.4f * LOG2E * satt[ch + 2], 0.4f * LOG2E * satt[ch + 3]};
    f32x2 a04_45 = {0.4f * LOG2E * satt[ch + 4], 0.4f * LOG2E * satt[ch + 5]};
    f32x2 a04_67 = {0.4f * LOG2E * satt[ch + 6], 0.4f * LOG2E * satt[ch + 7]};

    float ssum = 0.f;
    f32x2 ac01 = {0.f, 0.f}, ac23 = {0.f, 0.f}, ac45 = {0.f, 0.f}, ac67 = {0.f, 0.f};
    for (int p = p0; p < p1; p += 32) {
        int cnt = min(32, p1 - p);
        int srcs = (ln < cnt) ? csr_src[p + ln] : 0;
        int j = 0;
        for (; j + 8 <= cnt; j += 8) {
            int sa = __shfl(srcs, hbase + j + es);
            uint4 Ra = *(const uint4*)(xl2b + (size_t)sa * 32 + ch);
            G2_PROC(Ra, 0, 0)
        }
        if (j < cnt) {
            int idx = j + es;
            int sa = __shfl(srcs, hbase + (idx & 31));
            uint4 Ra = *(const uint4*)(xl2b + (size_t)sa * 32 + ch);
            G2_PROC(Ra, idx, 1)
        }
    }
    float A0 = ac01.x, A1 = ac01.y, A2 = ac23.x, A3 = ac23.y;
    float A4 = ac45.x, A5 = ac45.y, A6 = ac67.x, A7 = ac67.y;
    for (int off = 4; off < 32; off <<= 1) {  // merge 8 edge slots within half-wave
        ssum += __shfl_xor(ssum, off);
        A0 += __shfl_xor(A0, off); A1 += __shfl_xor(A1, off);
        A2 += __shfl_xor(A2, off); A3 += __shfl_xor(A3, off);
        A4 += __shfl_xor(A4, off); A5 += __shfl_xor(A5, off);
        A6 += __shfl_xor(A6, off); A7 += __shfl_xor(A7, off);
    }
    float inv_s = (p1 > p0) ? __builtin_amdgcn_rcpf(ssum) : 0.f;
    float v0 = A0 * inv_s + sb[ch + 0], v1 = A1 * inv_s + sb[ch + 1];
    float v2 = A2 * inv_s + sb[ch + 2], v3 = A3 * inv_s + sb[ch + 3];
    float v4 = A4 * inv_s + sb[ch + 4], v5 = A5 * inv_s + sb[ch + 5];
    float v6 = A6 * inv_s + sb[ch + 6], v7 = A7 * inv_s + sb[ch + 7];
    float s8 = v0 + v1 + v2 + v3 + v4 + v5 + v6 + v7;
    s8 += __shfl_xor(s8, 1); s8 += __shfl_xor(s8, 2);
    float mu = s8 * (1.f / 32.f);
    float d0 = v0 - mu, d1 = v1 - mu, d2 = v2 - mu, d3 = v3 - mu;
    float d4 = v4 - mu, d5 = v5 - mu, d6 = v6 - mu, d7 = v7 - mu;
    float q8 = d0 * d0 + d1 * d1 + d2 * d2 + d3 * d3 + d4 * d4 + d5 * d5 + d6 * d6 + d7 * d7;
    q8 += __shfl_xor(q8, 1); q8 += __shfl_xor(q8, 2);
    float inv = __builtin_amdgcn_rsqf(q8 * (1.f / 32.f) + 1e-5f);
    if (es == 0) {
        float4 oa, ob;
        oa.x = d0 * inv * sg[ch + 0] + sbe[ch + 0];
        oa.y = d1 * inv * sg[ch + 1] + sbe[ch + 1];
        oa.z = d2 * inv * sg[ch + 2] + sbe[ch + 2];
        oa.w = d3 * inv * sg[ch + 3] + sbe[ch + 3];
        ob.x = d4 * inv * sg[ch + 4] + sbe[ch + 4];
        ob.y = d5 * inv * sg[ch + 5] + sbe[ch + 5];
        ob.z = d6 * inv * sg[ch + 6] + sbe[ch + 6];
        ob.w = d7 * inv * sg[ch + 7] + sbe[ch + 7];
        *(float4*)(out + (size_t)node * 32 + ch) = oa;
        *(float4*)(out + (size_t)node * 32 + ch + 4) = ob;
    }
}

extern "C" void kernel_launch(void* const* d_in, const int* in_sizes, int n_in,
                              void* d_out, int out_size, void* d_ws, size_t ws_size,
                              hipStream_t stream) {
    const float* x    = (const float*)d_in[0];
    const int* ei     = (const int*)d_in[1];
    const float* Wl1  = (const float*)d_in[2];
    const float* Wr1  = (const float*)d_in[3];
    const float* att1 = (const float*)d_in[4];
    const float* b1   = (const float*)d_in[5];
    const float* g1   = (const float*)d_in[6];
    const float* be1  = (const float*)d_in[7];
    const float* Wl2  = (const float*)d_in[8];
    const float* Wr2  = (const float*)d_in[9];
    const float* att2 = (const float*)d_in[10];
    const float* b2   = (const float*)d_in[11];
    const float* g2   = (const float*)d_in[12];
    const float* be2  = (const float*)d_in[13];
    float* out = (float*)d_out;

    char* W = (char*)d_ws;
    unsigned short* xl2b = (unsigned short*)W;               // N*32 bf16 = 6.4 MB
    float* xr2 = (float*)(W + 6400000);                      // N*32 f32 = 12.8 MB
    int* rowptr = (int*)(W + 19200000);                      // N+1
    int* csr_src = rowptr + NN + 1;                          // E
    unsigned int* staging = (unsigned int*)(csr_src + NE);   // NBUCK*MAXB = 8 MB
    int* gcount = (int*)(staging + (size_t)NBUCK * MAXB);    // NBUCK

    const int B = 256;

    // ---- CSR build: 2 kernels + memset ----
    hipMemsetAsync(gcount, 0, NBUCK * sizeof(int), stream);
    bucketB_kernel<<<NPB, B, 0, stream>>>(ei, gcount, staging);
    bucketC_kernel<<<NBUCK, B, 0, stream>>>(staging, gcount, rowptr, csr_src);

    // ---- layer 1 (fused gather + LN + ELU + lin2, barrier-free) ----
    gather1_kernel<<<NN / 8, B, 0, stream>>>(rowptr, csr_src, x, Wl1, Wr1, att1,
                                             b1, g1, be1, Wl2, Wr2, xl2b, xr2);

    // ---- layer 2 ----
    gather2_kernel<<<NN / 8, B, 0, stream>>>(rowptr, csr_src, xl2b, xr2, att2,
                                             b2, g2, be2, out);
}